// Round 8
// baseline (7395.110 us; speedup 1.0000x reference)
//
#include <hip/hip_runtime.h>

typedef __bf16 bf16;
typedef bf16 bf16x8 __attribute__((ext_vector_type(8)));
typedef bf16 bf16x4 __attribute__((ext_vector_type(4)));
typedef float f32x4 __attribute__((ext_vector_type(4)));
typedef unsigned long long u64;

#define MFMA16(a,b,c) __builtin_amdgcn_mfma_f32_16x16x32_bf16((a),(b),(c),0,0,0)

#define B_N 256
#define T_N 512
#define H_N 768
#define WROW 776      // 768 + 8 pad
#define WIHROW 40     // 32 + 8 pad

// ---- device-global scratch (BSS) ----
__device__ float    g_ctrl[B_N * T_N];          // 512 KB
__device__ bf16     g_hbuf[2 * B_N * H_N];      // 768 KB (bf16 h exchange via MALL atomics)
__device__ unsigned g_flag[256];                // 8 groups x 32 flags (128B/group)

__device__ __forceinline__ float sigmoidf_(float x){ return 1.f/(1.f+__expf(-x)); }
__device__ __forceinline__ float tanhf_(float x){
  float e = __expf(-2.f*fabsf(x));
  float t = (1.f-e)/(1.f+e);
  return copysignf(t, x);
}
__device__ __forceinline__ float softplusf_(float x){
  return x > 20.f ? x : log1pf(__expf(x));
}

__global__ void k_zero() {
  if (threadIdx.x < 256) g_flag[threadIdx.x] = 0u;
}

// ---------------- kernel A: causal encoder Z + ctrl term ----------------
__global__ __launch_bounds__(256) void k_encode(
    const float* __restrict__ Xm, const float* __restrict__ Xc,
    const float* __restrict__ Aw,
    const float* __restrict__ ew1, const float* __restrict__ eb1,
    const float* __restrict__ ew2, const float* __restrict__ eb2,
    const float* __restrict__ nw,  const float* __restrict__ nb,
    const float* __restrict__ cw,  const float* __restrict__ cb,
    float* __restrict__ Zout)
{
  __shared__ float sA[16][16], sE1[16][32], sE2[16][16], sNW[16][32];
  __shared__ float sEB1[16], sEB2[16], sNB[16];
  __shared__ float sCW[768][16];
  __shared__ float sCB[768];
  const int tid = threadIdx.x;
  for (int i = tid; i < 256; i += 256) sA[i>>4][i&15] = Aw[i];
  for (int i = tid; i < 512; i += 256) sE1[i>>5][i&31] = ew1[i];
  for (int i = tid; i < 256; i += 256) sE2[i>>4][i&15] = ew2[i];
  for (int i = tid; i < 512; i += 256) sNW[i>>5][i&31] = nw[i];
  if (tid < 16) { sEB1[tid]=eb1[tid]; sEB2[tid]=eb2[tid]; sNB[tid]=nb[tid]; }
  for (int i = tid; i < 768*16; i += 256) sCW[i>>4][i&15] = cw[i];
  for (int i = tid; i < 768; i += 256) sCB[i] = cb[i];
  __syncthreads();
  const int idx = blockIdx.x*256 + tid;           // flat (b*T + t)
  const float* xmp = Xm + (size_t)idx*16;
  const float* xcp = Xc + (size_t)idx*16;
  float xm[16], xc[16];
  #pragma unroll
  for (int j=0;j<4;j++){
    *(f32x4*)&xm[j*4] = *(const f32x4*)(xmp + j*4);
    *(f32x4*)&xc[j*4] = *(const f32x4*)(xcp + j*4);
  }
  float snd[16], rcv[16];
  #pragma unroll
  for (int i=0;i<16;i++){
    float s=0.f, r=0.f;
    #pragma unroll
    for (int j=0;j<16;j++){ s += xm[j]*sA[i][j]; r += xm[j]*sA[j][i]; }
    snd[i]=s; rcv[i]=r;
  }
  float he[16];
  #pragma unroll
  for (int i=0;i<16;i++){
    float a = sEB1[i];
    #pragma unroll
    for (int k=0;k<16;k++) a += snd[k]*sE1[i][k];
    #pragma unroll
    for (int k=0;k<16;k++) a += rcv[k]*sE1[i][16+k];
    he[i] = fmaxf(a, 0.f);
  }
  float he2[16];
  #pragma unroll
  for (int i=0;i<16;i++){
    float a = sEB2[i];
    #pragma unroll
    for (int k=0;k<16;k++) a += he[k]*sE2[i][k];
    he2[i] = fmaxf(a, 0.f);
  }
  float* zp = Zout + (size_t)idx*16;
  #pragma unroll
  for (int m=0;m<16;m++){
    float a = sNB[m];
    #pragma unroll
    for (int k=0;k<16;k++) a += xm[k]*sNW[m][k];
    #pragma unroll
    for (int k=0;k<16;k++) a += he2[k]*sNW[m][16+k];
    zp[m] = fmaxf(a, 0.f);
  }
  float cs = 0.f;
  for (int i=0;i<768;i++){
    float a = sCB[i];
    #pragma unroll
    for (int k=0;k<16;k++) a += xc[k]*sCW[i][k];
    cs += fmaxf(a, 0.f);
  }
  g_ctrl[idx] = cs * 0.3f;
}

// ---------------- kernel B: adstock scan + hill + gru-input ----------------
__global__ __launch_bounds__(64) void k_adstock(
    const float* __restrict__ Xm, const float* __restrict__ alpha,
    const float* __restrict__ hill_a, const float* __restrict__ hill_g,
    float* __restrict__ Zio, float* __restrict__ hill_out)
{
  const int gid = blockIdx.x*64 + threadIdx.x;   // (b, m)
  const int b = gid >> 4, m = gid & 15;
  float a  = fminf(fmaxf(alpha[m],  0.f),  1.f);
  float ha = fminf(fmaxf(hill_a[m], 0.1f), 3.f);
  float hg = fminf(fmaxf(hill_g[m], 0.1f), 2.f);
  float gpow = __powf(hg, ha);
  const float* xp = Xm + (size_t)b*T_N*16 + m;
  float prev = 0.f, cmax = 0.f;
  for (int t=0;t<T_N;t++){ float x = xp[(size_t)t*16]; prev = x + a*prev; cmax = fmaxf(cmax, prev); }
  cmax = fmaxf(cmax, 1e-6f);
  float inv = 1.f/cmax;
  prev = 0.f;
  float* zp  = Zio      + (size_t)b*T_N*16 + m;
  float* hp  = hill_out + (size_t)b*T_N*16 + m;
  for (int t=0;t<T_N;t++){
    float x = xp[(size_t)t*16];
    prev = x + a*prev;
    float xn  = fmaxf(prev*inv, 0.f);
    float num = __powf(xn, ha);
    float h   = num / (num + gpow + 1e-8f);
    float z   = zp[(size_t)t*16];
    hp[(size_t)t*16] = h;
    zp[(size_t)t*16] = h + z;
  }
}

// ---------------- kernel C: persistent GRU + fused heads ----------------
// 8 groups x 32 blocks; block p owns h-dims [p*24,(p+1)*24). h exchange via
// relaxed agent-scope atomics (MALL). Per-wave flag polling; gi / hill / ctrl
// software-pipelined into the barrier wait window.
__device__ __forceinline__ void poll_flags(unsigned* flags, unsigned val, int lane) {
  const int idx = lane & 31;
  int tries = 0;
  for (;;) {
    unsigned v = __hip_atomic_load(&flags[idx], __ATOMIC_RELAXED, __HIP_MEMORY_SCOPE_AGENT);
    if (__ballot(v >= val) == ~0ull) break;
    if (++tries > 8) __builtin_amdgcn_s_sleep(1);
  }
  __builtin_amdgcn_fence(__ATOMIC_ACQUIRE, "workgroup");  // order, no L2 traffic
}

__global__ __launch_bounds__(256, 1) void k_gru(
    const float* __restrict__ Xc,
    const float* __restrict__ Wih, const float* __restrict__ Whh,
    const float* __restrict__ bih, const float* __restrict__ bhh,
    const float* __restrict__ wraww, const float* __restrict__ wrawb,
    const float* __restrict__ regemb, const float* __restrict__ bias,
    const float* __restrict__ h0,
    float* __restrict__ hillZ,       // = outw region (read until step t, then w_pos)
    float* __restrict__ hill,        // = outc region (read hill, overwrite contrib)
    float* __restrict__ outy)
{
  __shared__ __align__(16) bf16 sW[88*WROW];      // 136,576 B (72 Whh rows + 16 wraww)
  __shared__ __align__(16) bf16 sWih[72*WIHROW];  //   5,760 B
  __shared__ float sGH[32][84];                   //  10,752 B
  __shared__ float sGIN[32][36];                  //   4,608 B
  __shared__ float sHm[32][24];                   //   3,072 B (f32 master h slice)
  __shared__ float sHD[32][17];                   //   2,176 B (head MFMA D tile)
  __shared__ float sBih[72], sBhh[72];            //     576 B
  __shared__ float sWrb[16];                      //      64 B
  __shared__ float sScal[2];                      //       8 B   -> 163,592 total

  const int g = blockIdx.x & 7, p = blockIdx.x >> 3;
  const int j0 = p*24;
  const int tid = threadIdx.x;
  const int wave = tid >> 6, lane = tid & 63;
  const int quad = lane >> 4, l16 = lane & 15;

  // stage B-tile: rows 0..71 = Whh slice (f32->bf16), rows 72..87 = wraww
  for (int c = tid; c < 88*192; c += 256) {
    int rl = c / 192, off = (c - rl*192)*4;
    const float* src = (rl < 72)
        ? &Whh[(size_t)((rl/24)*768 + j0 + (rl%24))*768 + off]
        : &wraww[(size_t)(rl-72)*768 + off];
    f32x4 w = *(const f32x4*)src;
    bf16x4 v; v[0]=(bf16)w[0]; v[1]=(bf16)w[1]; v[2]=(bf16)w[2]; v[3]=(bf16)w[3];
    *(bf16x4*)&sW[rl*WROW + off] = v;
  }
  for (int c = tid; c < 72*8; c += 256) {
    int rl = c >> 3, off = (c & 7)*4;
    int grow = (rl/24)*768 + j0 + (rl%24);
    f32x4 w = *(const f32x4*)&Wih[(size_t)grow*32 + off];
    bf16x4 v; v[0]=(bf16)w[0]; v[1]=(bf16)w[1]; v[2]=(bf16)w[2]; v[3]=(bf16)w[3];
    *(bf16x4*)&sWih[rl*WIHROW + off] = v;
  }
  if (tid < 72) {
    int grow = (tid/24)*768 + j0 + (tid%24);
    sBih[tid] = bih[grow];
    sBhh[tid] = bhh[grow];
  }
  if (tid >= 128 && tid < 144) sWrb[tid-128] = wrawb[tid-128];
  if (wave == 0) {
    float s = 0.f;
    for (int k = lane; k < 768; k += 64) s += regemb[k];  // reg_emb[0]
    #pragma unroll
    for (int off = 32; off; off >>= 1) s += __shfl_xor(s, off, 64);
    if (lane == 0) { sScal[0] = 0.3f*s; sScal[1] = bias[0]; }
  }
  // init h (parity 0): f32 master + bf16 MALL publish (packed pairs)
  {
    unsigned* hb = (unsigned*)g_hbuf;
    for (int e = tid; e < 384; e += 256) {
      int b = e/12, j = (e - b*12)*2;
      float f0 = h0[j0+j], f1 = h0[j0+j+1];
      sHm[b][j] = f0; sHm[b][j+1] = f1;
      union { bf16 h[2]; unsigned u; } pk;
      pk.h[0] = (bf16)f0; pk.h[1] = (bf16)f1;
      __hip_atomic_store(&hb[((size_t)(g*32+b)*H_N + j0 + j) >> 1], pk.u,
                         __ATOMIC_RELAXED, __HIP_MEMORY_SCOPE_AGENT);
    }
  }
  unsigned* flags = g_flag + g*32;
  __syncthreads();   // drains init publishes + LDS staging
  if (tid == 0)
    __hip_atomic_store(&flags[p], 1u, __ATOMIC_RELAXED, __HIP_MEMORY_SCOPE_AGENT);

  const int mi = wave >> 1;
  const bool lowN = !(wave & 1);
  const int batch_l = l16 + mi*16;
  const int gb = g*32 + batch_l;
  const int bq = g*32 + p;
  const float regt = sScal[0], bias0 = sScal[1];
  const int r0 = lowN ? l16        : 48 + l16;
  const int r1 = lowN ? 16 + l16   : min(64 + l16, 71);
  const int r2 = 32 + l16;                 // lowN only
  const int rh = 72 + l16;                 // head rows (hiN only)
  float wp0_r = 0.f, hl0_r = 0.f, ct0_r = 0.f;  // t=0 state (lanes tid<16)

  // prologue: prefetch x(0)
  f32x4 xf0, xf1;
  {
    const float* hz = hillZ + (size_t)gb*T_N*16;
    const float* xr = Xc    + (size_t)gb*T_N*16;
    const float* src = (quad < 2) ? (hz + quad*8) : (xr + (quad-2)*8);
    xf0 = *(const f32x4*)src;
    xf1 = *(const f32x4*)(src + 4);
  }
  float hl_pf = 0.f, ct_pf = 0.f;

  int par = 0;
  for (int t = 0; t < T_N; t++) {
    f32x4 a0 = {0.f,0.f,0.f,0.f}, a1 = a0, a2 = a0, gi0 = a0, gi1 = a0, hd = a0;
    // gi = x @ W_ih^T from prefetched regs — runs in the barrier wait window
    {
      bf16x8 ax;
      ax[0]=(bf16)xf0[0]; ax[1]=(bf16)xf0[1]; ax[2]=(bf16)xf0[2]; ax[3]=(bf16)xf0[3];
      ax[4]=(bf16)xf1[0]; ax[5]=(bf16)xf1[1]; ax[6]=(bf16)xf1[2]; ax[7]=(bf16)xf1[3];
      if (lowN) {
        a0 = MFMA16(ax, *(const bf16x8*)&sWih[r0*WIHROW + quad*8], a0);
        a1 = MFMA16(ax, *(const bf16x8*)&sWih[r1*WIHROW + quad*8], a1);
        a2 = MFMA16(ax, *(const bf16x8*)&sWih[r2*WIHROW + quad*8], a2);
      } else {
        gi0 = MFMA16(ax, *(const bf16x8*)&sWih[r0*WIHROW + quad*8], gi0);
        gi1 = MFMA16(ax, *(const bf16x8*)&sWih[r1*WIHROW + quad*8], gi1);
      }
    }
    // per-wave barrier poll: h_{t-1} fully published when all flags >= t+1
    poll_flags(flags, (unsigned)(t + 1), lane);
    // h volley (critical path), then next-step prefetches (off-path)
    bf16x8 hf[24];
    {
      u64* hrow = (u64*)(g_hbuf + (size_t)par*B_N*H_N + (size_t)gb*H_N);
      #pragma unroll
      for (int kt = 0; kt < 24; kt++) {
        union { u64 q[2]; bf16x8 v; } f;
        f.q[0] = __hip_atomic_load(hrow + kt*8 + quad*2,     __ATOMIC_RELAXED, __HIP_MEMORY_SCOPE_AGENT);
        f.q[1] = __hip_atomic_load(hrow + kt*8 + quad*2 + 1, __ATOMIC_RELAXED, __HIP_MEMORY_SCOPE_AGENT);
        hf[kt] = f.v;
      }
    }
    {
      const int tn = (t + 1 < T_N) ? t + 1 : T_N - 1;
      const float* hz = hillZ + ((size_t)gb*T_N + tn)*16;
      const float* xr = Xc    + ((size_t)gb*T_N + tn)*16;
      const float* src = (quad < 2) ? (hz + quad*8) : (xr + (quad-2)*8);
      xf0 = *(const f32x4*)src;
      xf1 = *(const f32x4*)(src + 4);
    }
    if (tid < 16) {
      const int tt0 = (t > 0) ? t - 1 : 0;
      hl_pf = hill[((size_t)bq*T_N + tt0)*16 + tid];
      if (tid == 0) ct_pf = g_ctrl[(size_t)bq*T_N + tt0];
    }
    // gh += h @ W_hh^T over K=768
    #pragma unroll
    for (int kt = 0; kt < 24; kt++) {
      const int ko = kt*32 + quad*8;
      a0 = MFMA16(hf[kt], *(const bf16x8*)&sW[r0*WROW + ko], a0);
      a1 = MFMA16(hf[kt], *(const bf16x8*)&sW[r1*WROW + ko], a1);
      if (lowN) a2 = MFMA16(hf[kt], *(const bf16x8*)&sW[r2*WROW + ko], a2);
      else      hd = MFMA16(hf[kt], *(const bf16x8*)&sW[rh*WROW + ko], hd);
    }
    // stage D fragments
    {
      const int rb = mi*16 + quad*4;
      const int c0 = lowN ? l16 : 48 + l16;
      const int c1 = lowN ? 16 + l16 : 64 + l16;
      #pragma unroll
      for (int r = 0; r < 4; r++) {
        sGH[rb + r][c0] = a0[r];
        sGH[rb + r][c1] = a1[r];
        if (lowN) sGH[rb + r][32 + l16] = a2[r];
        else { sGIN[rb + r][l16] = gi0[r]; sGIN[rb + r][16 + l16] = gi1[r];
               sHD[rb + r][l16] = hd[r]; }
      }
    }
    __syncthreads();   // S1
    // epilogue (lanes 0..15) runs concurrently with gates (threads 32..255)
    if (t > 0 && tid < 16) {
      const int tt = t - 1;
      float wp = softplusf_(sHD[p][tid] + sWrb[tid]);
      float hl = hl_pf;
      if (tt == 0) { wp0_r = wp; hl0_r = hl; ct0_r = ct_pf; }
      else {
        size_t o = (size_t)bq*T_N + tt;
        float cv = hl*wp;
        hillZ[o*16 + tid] = wp;
        hill[o*16 + tid]  = cv;
        float cs = cv;
        cs += __shfl_xor(cs, 8, 64);
        cs += __shfl_xor(cs, 4, 64);
        cs += __shfl_xor(cs, 2, 64);
        cs += __shfl_xor(cs, 1, 64);
        if (tid == 0) outy[o] = cs + ct_pf + regt + bias0;
        if (tt == 1) {
          float w0 = 0.5f*(wp + wp0_r);
          float c0v = hl0_r*w0;
          size_t o0 = (size_t)bq*T_N;
          hillZ[o0*16 + tid] = w0;
          hill[o0*16 + tid]  = c0v;
          float cs0 = c0v;
          cs0 += __shfl_xor(cs0, 8, 64);
          cs0 += __shfl_xor(cs0, 4, 64);
          cs0 += __shfl_xor(cs0, 2, 64);
          cs0 += __shfl_xor(cs0, 1, 64);
          if (tid == 0) outy[o0] = cs0 + ct0_r + regt + bias0;
        }
      }
    }
    // gates -> h_new (pairs); f32 master feedback; bf16 MALL publish
    if (tid >= 32) {
      unsigned* hnxt = (unsigned*)(g_hbuf + (size_t)(1-par)*B_N*H_N);
      for (int e = tid - 32; e < 384; e += 224) {
        int b = e/12, j = (e - b*12)*2;
        float hn0, hn1;
        {
          float rr = sigmoidf_(sGH[b][j]    + sBih[j]    + sBhh[j]);
          float zz = sigmoidf_(sGH[b][24+j] + sBih[24+j] + sBhh[24+j]);
          float hh = sGH[b][48+j] + sBhh[48+j];
          float in_ = sGIN[b][j]  + sBih[48+j];
          float nn = tanhf_(in_ + rr*hh);
          hn0 = (1.f-zz)*nn + zz*sHm[b][j];
        }
        {
          int j1 = j+1;
          float rr = sigmoidf_(sGH[b][j1]    + sBih[j1]    + sBhh[j1]);
          float zz = sigmoidf_(sGH[b][24+j1] + sBih[24+j1] + sBhh[24+j1]);
          float hh = sGH[b][48+j1] + sBhh[48+j1];
          float in_ = sGIN[b][j1]  + sBih[48+j1];
          float nn = tanhf_(in_ + rr*hh);
          hn1 = (1.f-zz)*nn + zz*sHm[b][j1];
        }
        sHm[b][j] = hn0; sHm[b][j+1] = hn1;
        union { bf16 h[2]; unsigned u; } pk;
        pk.h[0] = (bf16)hn0; pk.h[1] = (bf16)hn1;
        __hip_atomic_store(&hnxt[((size_t)(g*32+b)*H_N + j0 + j) >> 1], pk.u,
                           __ATOMIC_RELAXED, __HIP_MEMORY_SCOPE_AGENT);
      }
    }
    __syncthreads();   // S2: drains all publishes (vmcnt(0) per wave)
    if (tid == 0)
      __hip_atomic_store(&flags[p], (unsigned)(t + 2), __ATOMIC_RELAXED, __HIP_MEMORY_SCOPE_AGENT);
    par ^= 1;
  }
  // tail: head for tt = T-1 from h_seq[T-1]
  if (wave & 1) {
    poll_flags(flags, (unsigned)(T_N + 1), lane);
    u64* hrow = (u64*)(g_hbuf + (size_t)par*B_N*H_N + (size_t)gb*H_N);
    f32x4 hd = {0.f,0.f,0.f,0.f};
    bf16x8 hf[24];
    #pragma unroll
    for (int kt = 0; kt < 24; kt++) {
      union { u64 q[2]; bf16x8 v; } f;
      f.q[0] = __hip_atomic_load(hrow + kt*8 + quad*2,     __ATOMIC_RELAXED, __HIP_MEMORY_SCOPE_AGENT);
      f.q[1] = __hip_atomic_load(hrow + kt*8 + quad*2 + 1, __ATOMIC_RELAXED, __HIP_MEMORY_SCOPE_AGENT);
      hf[kt] = f.v;
    }
    #pragma unroll
    for (int kt = 0; kt < 24; kt++) {
      const int ko = kt*32 + quad*8;
      hd = MFMA16(hf[kt], *(const bf16x8*)&sW[rh*WROW + ko], hd);
    }
    const int rb = mi*16 + quad*4;
    #pragma unroll
    for (int r = 0; r < 4; r++) sHD[rb + r][l16] = hd[r];
  }
  __syncthreads();
  if (tid < 16) {
    const int tt = T_N - 1;
    float wp = softplusf_(sHD[p][tid] + sWrb[tid]);
    float hl = hill[((size_t)bq*T_N + tt)*16 + tid];
    size_t o = (size_t)bq*T_N + tt;
    float cv = hl*wp;
    hillZ[o*16 + tid] = wp;
    hill[o*16 + tid]  = cv;
    float cs = cv;
    cs += __shfl_xor(cs, 8, 64);
    cs += __shfl_xor(cs, 4, 64);
    cs += __shfl_xor(cs, 2, 64);
    cs += __shfl_xor(cs, 1, 64);
    if (tid == 0) outy[o] = cs + g_ctrl[o] + regt + bias0;
  }
}

extern "C" void kernel_launch(void* const* d_in, const int* in_sizes, int n_in,
                              void* d_out, int out_size, void* d_ws, size_t ws_size,
                              hipStream_t stream) {
  const float* Xm    = (const float*)d_in[0];
  const float* Xc    = (const float*)d_in[1];
  const float* Aw    = (const float*)d_in[3];
  const float* ew1   = (const float*)d_in[4];
  const float* eb1   = (const float*)d_in[5];
  const float* ew2   = (const float*)d_in[6];
  const float* eb2   = (const float*)d_in[7];
  const float* nw    = (const float*)d_in[8];
  const float* nb    = (const float*)d_in[9];
  const float* Wih   = (const float*)d_in[10];
  const float* Whh   = (const float*)d_in[11];
  const float* bih   = (const float*)d_in[12];
  const float* bhh   = (const float*)d_in[13];
  const float* wraww = (const float*)d_in[14];
  const float* wrawb = (const float*)d_in[15];
  const float* alpha = (const float*)d_in[16];
  const float* hilla = (const float*)d_in[17];
  const float* hillg = (const float*)d_in[18];
  const float* cw    = (const float*)d_in[19];
  const float* cb    = (const float*)d_in[20];
  const float* regemb= (const float*)d_in[21];
  const float* bias  = (const float*)d_in[22];
  const float* h0    = (const float*)d_in[23];

  float* outy = (float*)d_out;
  float* outw = outy + 256*512;          // doubles as Z / hillZ scratch
  float* outc = outw + 256*512*16;       // doubles as hill scratch

  k_zero<<<1, 256, 0, stream>>>();
  k_encode<<<512, 256, 0, stream>>>(Xm, Xc, Aw, ew1, eb1, ew2, eb2, nw, nb, cw, cb,
                                    outw);
  k_adstock<<<64, 64, 0, stream>>>(Xm, alpha, hilla, hillg, outw, outc);
  void* args[] = { (void*)&Xc, (void*)&Wih, (void*)&Whh, (void*)&bih, (void*)&bhh,
                   (void*)&wraww, (void*)&wrawb, (void*)&regemb, (void*)&bias, (void*)&h0,
                   (void*)&outw, (void*)&outc, (void*)&outy };
  (void)hipLaunchCooperativeKernel((void*)k_gru, dim3(256), dim3(256), args, 0, stream);
}

// Round 10
// 4048.681 us; speedup vs baseline: 1.8265x; 1.8265x over previous
//
#include <hip/hip_runtime.h>

typedef __bf16 bf16;
typedef bf16 bf16x8 __attribute__((ext_vector_type(8)));
typedef bf16 bf16x4 __attribute__((ext_vector_type(4)));
typedef float f32x4 __attribute__((ext_vector_type(4)));

#define MFMA16(a,b,c) __builtin_amdgcn_mfma_f32_16x16x32_bf16((a),(b),(c),0,0,0)

#define B_N 256
#define T_N 512
#define H_N 768
#define WROW 776      // 768 + 8 pad
#define WIHROW 40     // 32 + 8 pad

// ---- device-global scratch (BSS) ----
__device__ float    g_ctrl[B_N * T_N];          // 512 KB
__device__ bf16     g_hbuf[2 * B_N * H_N];      // 768 KB (bf16 h exchange, intra-XCD L2)
__device__ unsigned g_flag[256 * 32];           // 32 KB: per-BLOCK flag, 128B apart
__device__ unsigned g_members[8 * 32];          // XCD roster -> blockIdx table
__device__ unsigned g_roster[8];
__device__ unsigned g_sync;

__device__ __forceinline__ float sigmoidf_(float x){ return 1.f/(1.f+__expf(-x)); }
__device__ __forceinline__ float tanhf_(float x){
  float e = __expf(-2.f*fabsf(x));
  float t = (1.f-e)/(1.f+e);
  return copysignf(t, x);
}
__device__ __forceinline__ float softplusf_(float x){
  return x > 20.f ? x : log1pf(__expf(x));
}

__global__ void k_zero() {
  const int tid = threadIdx.x;
  for (int i = tid; i < 256*32; i += 256) g_flag[i] = 0u;
  if (tid < 256) g_members[tid & 255] = 0u;   // fallback: block 0's flag (always advances)
  if (tid < 8)   g_roster[tid] = 0u;
  if (tid == 0)  g_sync = 0u;
}

// ---------------- kernel A: causal encoder Z + ctrl term ----------------
__global__ __launch_bounds__(256) void k_encode(
    const float* __restrict__ Xm, const float* __restrict__ Xc,
    const float* __restrict__ Aw,
    const float* __restrict__ ew1, const float* __restrict__ eb1,
    const float* __restrict__ ew2, const float* __restrict__ eb2,
    const float* __restrict__ nw,  const float* __restrict__ nb,
    const float* __restrict__ cw,  const float* __restrict__ cb,
    float* __restrict__ Zout)
{
  __shared__ float sA[16][16], sE1[16][32], sE2[16][16], sNW[16][32];
  __shared__ float sEB1[16], sEB2[16], sNB[16];
  __shared__ float sCW[768][16];
  __shared__ float sCB[768];
  const int tid = threadIdx.x;
  for (int i = tid; i < 256; i += 256) sA[i>>4][i&15] = Aw[i];
  for (int i = tid; i < 512; i += 256) sE1[i>>5][i&31] = ew1[i];
  for (int i = tid; i < 256; i += 256) sE2[i>>4][i&15] = ew2[i];
  for (int i = tid; i < 512; i += 256) sNW[i>>5][i&31] = nw[i];
  if (tid < 16) { sEB1[tid]=eb1[tid]; sEB2[tid]=eb2[tid]; sNB[tid]=nb[tid]; }
  for (int i = tid; i < 768*16; i += 256) sCW[i>>4][i&15] = cw[i];
  for (int i = tid; i < 768; i += 256) sCB[i] = cb[i];
  __syncthreads();
  const int idx = blockIdx.x*256 + tid;           // flat (b*T + t)
  const float* xmp = Xm + (size_t)idx*16;
  const float* xcp = Xc + (size_t)idx*16;
  float xm[16], xc[16];
  #pragma unroll
  for (int j=0;j<4;j++){
    *(f32x4*)&xm[j*4] = *(const f32x4*)(xmp + j*4);
    *(f32x4*)&xc[j*4] = *(const f32x4*)(xcp + j*4);
  }
  float snd[16], rcv[16];
  #pragma unroll
  for (int i=0;i<16;i++){
    float s=0.f, r=0.f;
    #pragma unroll
    for (int j=0;j<16;j++){ s += xm[j]*sA[i][j]; r += xm[j]*sA[j][i]; }
    snd[i]=s; rcv[i]=r;
  }
  float he[16];
  #pragma unroll
  for (int i=0;i<16;i++){
    float a = sEB1[i];
    #pragma unroll
    for (int k=0;k<16;k++) a += snd[k]*sE1[i][k];
    #pragma unroll
    for (int k=0;k<16;k++) a += rcv[k]*sE1[i][16+k];
    he[i] = fmaxf(a, 0.f);
  }
  float he2[16];
  #pragma unroll
  for (int i=0;i<16;i++){
    float a = sEB2[i];
    #pragma unroll
    for (int k=0;k<16;k++) a += he[k]*sE2[i][k];
    he2[i] = fmaxf(a, 0.f);
  }
  float* zp = Zout + (size_t)idx*16;
  #pragma unroll
  for (int m=0;m<16;m++){
    float a = sNB[m];
    #pragma unroll
    for (int k=0;k<16;k++) a += xm[k]*sNW[m][k];
    #pragma unroll
    for (int k=0;k<16;k++) a += he2[k]*sNW[m][16+k];
    zp[m] = fmaxf(a, 0.f);
  }
  float cs = 0.f;
  for (int i=0;i<768;i++){
    float a = sCB[i];
    #pragma unroll
    for (int k=0;k<16;k++) a += xc[k]*sCW[i][k];
    cs += fmaxf(a, 0.f);
  }
  g_ctrl[idx] = cs * 0.3f;
}

// ---------------- kernel B: adstock scan + hill + gru-input ----------------
__global__ __launch_bounds__(64) void k_adstock(
    const float* __restrict__ Xm, const float* __restrict__ alpha,
    const float* __restrict__ hill_a, const float* __restrict__ hill_g,
    float* __restrict__ Zio, float* __restrict__ hill_out)
{
  const int gid = blockIdx.x*64 + threadIdx.x;   // (b, m)
  const int b = gid >> 4, m = gid & 15;
  float a  = fminf(fmaxf(alpha[m],  0.f),  1.f);
  float ha = fminf(fmaxf(hill_a[m], 0.1f), 3.f);
  float hg = fminf(fmaxf(hill_g[m], 0.1f), 2.f);
  float gpow = __powf(hg, ha);
  const float* xp = Xm + (size_t)b*T_N*16 + m;
  float prev = 0.f, cmax = 0.f;
  for (int t=0;t<T_N;t++){ float x = xp[(size_t)t*16]; prev = x + a*prev; cmax = fmaxf(cmax, prev); }
  cmax = fmaxf(cmax, 1e-6f);
  float inv = 1.f/cmax;
  prev = 0.f;
  float* zp  = Zio      + (size_t)b*T_N*16 + m;
  float* hp  = hill_out + (size_t)b*T_N*16 + m;
  for (int t=0;t<T_N;t++){
    float x = xp[(size_t)t*16];
    prev = x + a*prev;
    float xn  = fmaxf(prev*inv, 0.f);
    float num = __powf(xn, ha);
    float h   = num / (num + gpow + 1e-8f);
    float z   = zp[(size_t)t*16];
    hp[(size_t)t*16] = h;
    zp[(size_t)t*16] = h + z;
  }
}

// ---------------- kernel C: persistent GRU + fused heads ----------------
// Groups = physical XCDs (HW_REG_XCC_ID roster; 160KB LDS forces 1 block/CU,
// cooperative 256 blocks = 32 blocks/XCD). h exchange: plain stores
// (write-through L1 -> XCD L2) + sc0 L1-bypass loads. Flags: per-BLOCK slots
// via MALL agent atomics (unique writer -> never orphaned); members polled
// through a discovered roster table; timeout makes any error fail-visible.
__device__ __forceinline__ void poll_flags(unsigned midx, unsigned val) {
  int tries = 0;
  for (;;) {
    unsigned v = __hip_atomic_load(&g_flag[midx], __ATOMIC_RELAXED, __HIP_MEMORY_SCOPE_AGENT);
    if (__ballot(v >= val) == ~0ull) break;
    if (++tries > (1<<18)) break;               // fail-visible, never hang
    if (tries > 8) __builtin_amdgcn_s_sleep(1);
  }
  __builtin_amdgcn_fence(__ATOMIC_ACQUIRE, "workgroup");
}

__global__ __launch_bounds__(256, 1) void k_gru(
    const float* __restrict__ Xc,
    const float* __restrict__ Wih, const float* __restrict__ Whh,
    const float* __restrict__ bih, const float* __restrict__ bhh,
    const float* __restrict__ wraww, const float* __restrict__ wrawb,
    const float* __restrict__ regemb, const float* __restrict__ bias,
    const float* __restrict__ h0,
    float* __restrict__ hillZ,       // = outw region (read until step t, then w_pos)
    float* __restrict__ hill,        // = outc region (read hill, overwrite contrib)
    float* __restrict__ outy)
{
  __shared__ __align__(16) bf16 sW[88*WROW];      // 136,576 B (72 Whh rows + 16 wraww)
  __shared__ __align__(16) bf16 sWih[72*WIHROW];  //   5,760 B
  __shared__ float sGH[32][84];                   //  10,752 B
  __shared__ float sGIN[32][36];                  //   4,608 B
  __shared__ float sHm[32][24];                   //   3,072 B (f32 master h slice)
  __shared__ float sHD[32][17];                   //   2,176 B (head MFMA D tile)
  __shared__ float sBih[72], sBhh[72];            //     576 B
  __shared__ float sWrb[16];                      //      64 B
  __shared__ float sScal[2];                      //       8 B
  __shared__ unsigned sGP[2];                     //       8 B  -> 163,600 total

  const int tid = threadIdx.x;
  const int wave = tid >> 6, lane = tid & 63;
  const int quad = lane >> 4, l16 = lane & 15;

  // runtime group discovery: g = physical XCD (assembler-encoded getreg)
  if (tid == 0) {
    unsigned x;
    asm volatile("s_getreg_b32 %0, hwreg(HW_REG_XCC_ID, 0, 32)" : "=s"(x));
    x &= 7u;
    unsigned slot = __hip_atomic_fetch_add(&g_roster[x], 1u,
                        __ATOMIC_RELAXED, __HIP_MEMORY_SCOPE_AGENT);
    if (slot < 32u)
      __hip_atomic_store(&g_members[x*32u + slot], (unsigned)blockIdx.x,
                         __ATOMIC_RELAXED, __HIP_MEMORY_SCOPE_AGENT);
    sGP[0] = x; sGP[1] = slot & 31u;
    // one-time grid barrier so all member tables are complete
    __hip_atomic_fetch_add(&g_sync, 1u, __ATOMIC_RELEASE, __HIP_MEMORY_SCOPE_AGENT);
    int tries = 0;
    while (__hip_atomic_load(&g_sync, __ATOMIC_ACQUIRE, __HIP_MEMORY_SCOPE_AGENT) < 256u) {
      if (++tries > (1<<20)) break;
      __builtin_amdgcn_s_sleep(1);
    }
  }
  __syncthreads();
  const int g = (int)sGP[0], p = (int)sGP[1];
  const int j0 = p*24;
  // my poll target: member (lane&31)'s flag slot
  const unsigned midx = __hip_atomic_load(&g_members[g*32 + (lane & 31)],
                            __ATOMIC_RELAXED, __HIP_MEMORY_SCOPE_AGENT) * 32u;
  const unsigned myflag = (unsigned)blockIdx.x * 32u;

  // stage B-tile: rows 0..71 = Whh slice (f32->bf16), rows 72..87 = wraww
  for (int c = tid; c < 88*192; c += 256) {
    int rl = c / 192, off = (c - rl*192)*4;
    const float* src = (rl < 72)
        ? &Whh[(size_t)((rl/24)*768 + j0 + (rl%24))*768 + off]
        : &wraww[(size_t)(rl-72)*768 + off];
    f32x4 w = *(const f32x4*)src;
    bf16x4 v; v[0]=(bf16)w[0]; v[1]=(bf16)w[1]; v[2]=(bf16)w[2]; v[3]=(bf16)w[3];
    *(bf16x4*)&sW[rl*WROW + off] = v;
  }
  for (int c = tid; c < 72*8; c += 256) {
    int rl = c >> 3, off = (c & 7)*4;
    int grow = (rl/24)*768 + j0 + (rl%24);
    f32x4 w = *(const f32x4*)&Wih[(size_t)grow*32 + off];
    bf16x4 v; v[0]=(bf16)w[0]; v[1]=(bf16)w[1]; v[2]=(bf16)w[2]; v[3]=(bf16)w[3];
    *(bf16x4*)&sWih[rl*WIHROW + off] = v;
  }
  if (tid < 72) {
    int grow = (tid/24)*768 + j0 + (tid%24);
    sBih[tid] = bih[grow];
    sBhh[tid] = bhh[grow];
  }
  if (tid >= 128 && tid < 144) sWrb[tid-128] = wrawb[tid-128];
  if (wave == 0) {
    float s = 0.f;
    for (int k = lane; k < 768; k += 64) s += regemb[k];  // reg_emb[0]
    #pragma unroll
    for (int off = 32; off; off >>= 1) s += __shfl_xor(s, off, 64);
    if (lane == 0) { sScal[0] = 0.3f*s; sScal[1] = bias[0]; }
  }
  // init h (parity 0): f32 master + bf16 publish (plain stores -> XCD L2)
  {
    unsigned* hb = (unsigned*)g_hbuf;
    for (int e = tid; e < 384; e += 256) {
      int b = e/12, j = (e - b*12)*2;
      float f0 = h0[j0+j], f1 = h0[j0+j+1];
      sHm[b][j] = f0; sHm[b][j+1] = f1;
      union { bf16 h[2]; unsigned u; } pk;
      pk.h[0] = (bf16)f0; pk.h[1] = (bf16)f1;
      hb[((size_t)(g*32+b)*H_N + j0 + j) >> 1] = pk.u;
    }
  }
  __syncthreads();   // drains init publishes (vmcnt(0)) + LDS staging
  if (tid == 0)
    __hip_atomic_store(&g_flag[myflag], 1u, __ATOMIC_RELAXED, __HIP_MEMORY_SCOPE_AGENT);

  const int mi = wave >> 1;
  const bool lowN = !(wave & 1);
  const int batch_l = l16 + mi*16;
  const int gb = g*32 + batch_l;
  const int bq = g*32 + p;
  const float regt = sScal[0], bias0 = sScal[1];
  const int r0 = lowN ? l16        : 48 + l16;
  const int r1 = lowN ? 16 + l16   : min(64 + l16, 71);
  const int r2 = 32 + l16;                 // lowN only
  const int rh = 72 + l16;                 // head rows (hiN only)
  float wp0_r = 0.f, hl0_r = 0.f, ct0_r = 0.f;  // t=0 state (lanes tid<16)

  // prologue: prefetch x(0) and hill/ctrl(0)
  f32x4 xf0, xf1;
  {
    const float* hz = hillZ + (size_t)gb*T_N*16;
    const float* xr = Xc    + (size_t)gb*T_N*16;
    const float* src = (quad < 2) ? (hz + quad*8) : (xr + (quad-2)*8);
    xf0 = *(const f32x4*)src;
    xf1 = *(const f32x4*)(src + 4);
  }
  float hl_pf = 0.f, ct_pf = 0.f;
  if (tid < 16) {
    hl_pf = hill[(size_t)bq*T_N*16 + tid];
    if (tid == 0) ct_pf = g_ctrl[(size_t)bq*T_N];
  }

  const bf16* hb_base = g_hbuf;
  int par = 0;
  for (int t = 0; t < T_N; t++) {
    f32x4 a0 = {0.f,0.f,0.f,0.f}, a1 = a0, a2 = a0, gi0 = a0, gi1 = a0, hd = a0;
    // gi = x @ W_ih^T from prefetched regs (overlaps the wait window)
    {
      bf16x8 ax;
      ax[0]=(bf16)xf0[0]; ax[1]=(bf16)xf0[1]; ax[2]=(bf16)xf0[2]; ax[3]=(bf16)xf0[3];
      ax[4]=(bf16)xf1[0]; ax[5]=(bf16)xf1[1]; ax[6]=(bf16)xf1[2]; ax[7]=(bf16)xf1[3];
      if (lowN) {
        a0 = MFMA16(ax, *(const bf16x8*)&sWih[r0*WIHROW + quad*8], a0);
        a1 = MFMA16(ax, *(const bf16x8*)&sWih[r1*WIHROW + quad*8], a1);
        a2 = MFMA16(ax, *(const bf16x8*)&sWih[r2*WIHROW + quad*8], a2);
      } else {
        gi0 = MFMA16(ax, *(const bf16x8*)&sWih[r0*WIHROW + quad*8], gi0);
        gi1 = MFMA16(ax, *(const bf16x8*)&sWih[r1*WIHROW + quad*8], gi1);
      }
    }
    // wait: all group members published h_{t-1}
    poll_flags(midx, (unsigned)(t + 1));
    // h volley: 24 x 16B sc0 loads (L1-bypass, XCD-L2 hit), waitcnt-pinned
    bf16x8 hf[24];
    {
      const bf16* hrow = hb_base + (size_t)par*B_N*H_N + (size_t)gb*H_N + quad*8;
      #pragma unroll
      for (int kt = 0; kt < 24; kt++) {
        asm volatile("global_load_dwordx4 %0, %1, off sc0"
                     : "=v"(hf[kt]) : "v"(hrow + kt*32) : "memory");
      }
      asm volatile("s_waitcnt vmcnt(0)"
          : "+v"(hf[0]),"+v"(hf[1]),"+v"(hf[2]),"+v"(hf[3]),
            "+v"(hf[4]),"+v"(hf[5]),"+v"(hf[6]),"+v"(hf[7]) :: "memory");
      asm volatile(""
          : "+v"(hf[8]),"+v"(hf[9]),"+v"(hf[10]),"+v"(hf[11]),
            "+v"(hf[12]),"+v"(hf[13]),"+v"(hf[14]),"+v"(hf[15]));
      asm volatile(""
          : "+v"(hf[16]),"+v"(hf[17]),"+v"(hf[18]),"+v"(hf[19]),
            "+v"(hf[20]),"+v"(hf[21]),"+v"(hf[22]),"+v"(hf[23]));
    }
    // next-step prefetches (latency hidden under MFMA burst)
    {
      const int tn = (t + 1 < T_N) ? t + 1 : T_N - 1;
      const float* hz = hillZ + ((size_t)gb*T_N + tn)*16;
      const float* xr = Xc    + ((size_t)gb*T_N + tn)*16;
      const float* src = (quad < 2) ? (hz + quad*8) : (xr + (quad-2)*8);
      xf0 = *(const f32x4*)src;
      xf1 = *(const f32x4*)(src + 4);
    }
    // gh += h @ W_hh^T over K=768 (+ head column on hiN waves)
    #pragma unroll
    for (int kt = 0; kt < 24; kt++) {
      const int ko = kt*32 + quad*8;
      a0 = MFMA16(hf[kt], *(const bf16x8*)&sW[r0*WROW + ko], a0);
      a1 = MFMA16(hf[kt], *(const bf16x8*)&sW[r1*WROW + ko], a1);
      if (lowN) a2 = MFMA16(hf[kt], *(const bf16x8*)&sW[r2*WROW + ko], a2);
      else      hd = MFMA16(hf[kt], *(const bf16x8*)&sW[rh*WROW + ko], hd);
    }
    // stage D fragments
    {
      const int rb = mi*16 + quad*4;
      const int c0 = lowN ? l16 : 48 + l16;
      const int c1 = lowN ? 16 + l16 : 64 + l16;
      #pragma unroll
      for (int r = 0; r < 4; r++) {
        sGH[rb + r][c0] = a0[r];
        sGH[rb + r][c1] = a1[r];
        if (lowN) sGH[rb + r][32 + l16] = a2[r];
        else { sGIN[rb + r][l16] = gi0[r]; sGIN[rb + r][16 + l16] = gi1[r];
               sHD[rb + r][l16] = hd[r]; }
      }
    }
    __syncthreads();   // S1
    // epilogue (lanes 0..15) concurrent with gates (threads 32..255)
    if (t > 0 && tid < 16) {
      const int tt = t - 1;
      float wp = softplusf_(sHD[p][tid] + sWrb[tid]);
      float hl = hl_pf;
      if (tt == 0) { wp0_r = wp; hl0_r = hl; ct0_r = ct_pf; }
      else {
        size_t o = (size_t)bq*T_N + tt;
        float cv = hl*wp;
        hillZ[o*16 + tid] = wp;
        hill[o*16 + tid]  = cv;
        float cs = cv;
        cs += __shfl_xor(cs, 8, 64);
        cs += __shfl_xor(cs, 4, 64);
        cs += __shfl_xor(cs, 2, 64);
        cs += __shfl_xor(cs, 1, 64);
        if (tid == 0) outy[o] = cs + ct_pf + regt + bias0;
        if (tt == 1) {
          float w0 = 0.5f*(wp + wp0_r);
          float c0v = hl0_r*w0;
          size_t o0 = (size_t)bq*T_N;
          hillZ[o0*16 + tid] = w0;
          hill[o0*16 + tid]  = c0v;
          float cs0 = c0v;
          cs0 += __shfl_xor(cs0, 8, 64);
          cs0 += __shfl_xor(cs0, 4, 64);
          cs0 += __shfl_xor(cs0, 2, 64);
          cs0 += __shfl_xor(cs0, 1, 64);
          if (tid == 0) outy[o0] = cs0 + ct0_r + regt + bias0;
        }
      }
    }
    // prefetch hill/ctrl for next epilogue (column t)
    if (tid < 16) {
      hl_pf = hill[((size_t)bq*T_N + t)*16 + tid];
      if (tid == 0) ct_pf = g_ctrl[(size_t)bq*T_N + t];
    }
    // gates -> h_new (pairs); f32 master feedback; plain-store publish (L2)
    if (tid >= 32) {
      unsigned* hnxt = (unsigned*)(g_hbuf + (size_t)(1-par)*B_N*H_N);
      for (int e = tid - 32; e < 384; e += 224) {
        int b = e/12, j = (e - b*12)*2;
        float hn0, hn1;
        {
          float rr = sigmoidf_(sGH[b][j]    + sBih[j]    + sBhh[j]);
          float zz = sigmoidf_(sGH[b][24+j] + sBih[24+j] + sBhh[24+j]);
          float hh = sGH[b][48+j] + sBhh[48+j];
          float in_ = sGIN[b][j]  + sBih[48+j];
          float nn = tanhf_(in_ + rr*hh);
          hn0 = (1.f-zz)*nn + zz*sHm[b][j];
        }
        {
          int j1 = j+1;
          float rr = sigmoidf_(sGH[b][j1]    + sBih[j1]    + sBhh[j1]);
          float zz = sigmoidf_(sGH[b][24+j1] + sBih[24+j1] + sBhh[24+j1]);
          float hh = sGH[b][48+j1] + sBhh[48+j1];
          float in_ = sGIN[b][j1]  + sBih[48+j1];
          float nn = tanhf_(in_ + rr*hh);
          hn1 = (1.f-zz)*nn + zz*sHm[b][j1];
        }
        sHm[b][j] = hn0; sHm[b][j+1] = hn1;
        union { bf16 h[2]; unsigned u; } pk;
        pk.h[0] = (bf16)hn0; pk.h[1] = (bf16)hn1;
        hnxt[((size_t)(g*32+b)*H_N + j0 + j) >> 1] = pk.u;
      }
    }
    __syncthreads();   // S2: vmcnt(0) drains publishes into L2
    if (tid == 0)
      __hip_atomic_store(&g_flag[myflag], (unsigned)(t + 2), __ATOMIC_RELAXED, __HIP_MEMORY_SCOPE_AGENT);
    par ^= 1;
  }
  // tail: head for tt = T-1 from h_seq[T-1]
  if (wave & 1) {
    poll_flags(midx, (unsigned)(T_N + 1));
    const bf16* hrow = hb_base + (size_t)par*B_N*H_N + (size_t)gb*H_N + quad*8;
    f32x4 hd = {0.f,0.f,0.f,0.f};
    bf16x8 hf[24];
    #pragma unroll
    for (int kt = 0; kt < 24; kt++) {
      asm volatile("global_load_dwordx4 %0, %1, off sc0"
                   : "=v"(hf[kt]) : "v"(hrow + kt*32) : "memory");
    }
    asm volatile("s_waitcnt vmcnt(0)"
        : "+v"(hf[0]),"+v"(hf[1]),"+v"(hf[2]),"+v"(hf[3]),
          "+v"(hf[4]),"+v"(hf[5]),"+v"(hf[6]),"+v"(hf[7]) :: "memory");
    asm volatile(""
        : "+v"(hf[8]),"+v"(hf[9]),"+v"(hf[10]),"+v"(hf[11]),
          "+v"(hf[12]),"+v"(hf[13]),"+v"(hf[14]),"+v"(hf[15]));
    asm volatile(""
        : "+v"(hf[16]),"+v"(hf[17]),"+v"(hf[18]),"+v"(hf[19]),
          "+v"(hf[20]),"+v"(hf[21]),"+v"(hf[22]),"+v"(hf[23]));
    #pragma unroll
    for (int kt = 0; kt < 24; kt++) {
      const int ko = kt*32 + quad*8;
      hd = MFMA16(hf[kt], *(const bf16x8*)&sW[rh*WROW + ko], hd);
    }
    const int rb = mi*16 + quad*4;
    #pragma unroll
    for (int r = 0; r < 4; r++) sHD[rb + r][l16] = hd[r];
  }
  __syncthreads();
  if (tid < 16) {
    const int tt = T_N - 1;
    float wp = softplusf_(sHD[p][tid] + sWrb[tid]);
    float hl = hill[((size_t)bq*T_N + tt)*16 + tid];
    size_t o = (size_t)bq*T_N + tt;
    float cv = hl*wp;
    hillZ[o*16 + tid] = wp;
    hill[o*16 + tid]  = cv;
    float cs = cv;
    cs += __shfl_xor(cs, 8, 64);
    cs += __shfl_xor(cs, 4, 64);
    cs += __shfl_xor(cs, 2, 64);
    cs += __shfl_xor(cs, 1, 64);
    if (tid == 0) outy[o] = cs + g_ctrl[o] + regt + bias0;
  }
}

extern "C" void kernel_launch(void* const* d_in, const int* in_sizes, int n_in,
                              void* d_out, int out_size, void* d_ws, size_t ws_size,
                              hipStream_t stream) {
  const float* Xm    = (const float*)d_in[0];
  const float* Xc    = (const float*)d_in[1];
  const float* Aw    = (const float*)d_in[3];
  const float* ew1   = (const float*)d_in[4];
  const float* eb1   = (const float*)d_in[5];
  const float* ew2   = (const float*)d_in[6];
  const float* eb2   = (const float*)d_in[7];
  const float* nw    = (const float*)d_in[8];
  const float* nb    = (const float*)d_in[9];
  const float* Wih   = (const float*)d_in[10];
  const float* Whh   = (const float*)d_in[11];
  const float* bih   = (const float*)d_in[12];
  const float* bhh   = (const float*)d_in[13];
  const float* wraww = (const float*)d_in[14];
  const float* wrawb = (const float*)d_in[15];
  const float* alpha = (const float*)d_in[16];
  const float* hilla = (const float*)d_in[17];
  const float* hillg = (const float*)d_in[18];
  const float* cw    = (const float*)d_in[19];
  const float* cb    = (const float*)d_in[20];
  const float* regemb= (const float*)d_in[21];
  const float* bias  = (const float*)d_in[22];
  const float* h0    = (const float*)d_in[23];

  float* outy = (float*)d_out;
  float* outw = outy + 256*512;          // doubles as Z / hillZ scratch
  float* outc = outw + 256*512*16;       // doubles as hill scratch

  k_zero<<<1, 256, 0, stream>>>();
  k_encode<<<512, 256, 0, stream>>>(Xm, Xc, Aw, ew1, eb1, ew2, eb2, nw, nb, cw, cb,
                                    outw);
  k_adstock<<<64, 64, 0, stream>>>(Xm, alpha, hilla, hillg, outw, outc);
  void* args[] = { (void*)&Xc, (void*)&Wih, (void*)&Whh, (void*)&bih, (void*)&bhh,
                   (void*)&wraww, (void*)&wrawb, (void*)&regemb, (void*)&bias, (void*)&h0,
                   (void*)&outw, (void*)&outc, (void*)&outy };
  (void)hipLaunchCooperativeKernel((void*)k_gru, dim3(256), dim3(256), args, 0, stream);
}

// Round 13
// 4041.089 us; speedup vs baseline: 1.8300x; 1.0019x over previous
//
#include <hip/hip_runtime.h>

typedef __bf16 bf16;
typedef bf16 bf16x8 __attribute__((ext_vector_type(8)));
typedef bf16 bf16x4 __attribute__((ext_vector_type(4)));
typedef float f32x4 __attribute__((ext_vector_type(4)));

#define MFMA16(a,b,c) __builtin_amdgcn_mfma_f32_16x16x32_bf16((a),(b),(c),0,0,0)

#define B_N 256
#define T_N 512
#define H_N 768
#define WROW 776      // 768 + 8 pad
#define WIHROW 40     // 32 + 8 pad

// ---- device-global scratch (BSS) ----
__device__ float    g_ctrl[B_N * T_N];          // 512 KB
__device__ bf16     g_hbuf[2 * B_N * H_N];      // 768 KB (bf16 h exchange, intra-XCD L2)
__device__ unsigned g_flag[256 * 32];           // per-BLOCK flag, 128B apart
__device__ unsigned g_members[8 * 32];          // XCD roster -> blockIdx table
__device__ unsigned g_roster[8];
__device__ unsigned g_sync;

__device__ __forceinline__ float sigmoidf_(float x){ return 1.f/(1.f+__expf(-x)); }
__device__ __forceinline__ float tanhf_(float x){
  float e = __expf(-2.f*fabsf(x));
  float t = (1.f-e)/(1.f+e);
  return copysignf(t, x);
}
__device__ __forceinline__ float softplusf_(float x){
  return x > 20.f ? x : log1pf(__expf(x));
}

__global__ void k_zero() {
  const int tid = threadIdx.x;
  for (int i = tid; i < 256*32; i += 256) g_flag[i] = 0u;
  if (tid < 256) g_members[tid & 255] = 0u;   // fallback: block 0's flag (always advances)
  if (tid < 8)   g_roster[tid] = 0u;
  if (tid == 0)  g_sync = 0u;
}

// ---------------- kernel A: causal encoder Z + ctrl term ----------------
__global__ __launch_bounds__(256) void k_encode(
    const float* __restrict__ Xm, const float* __restrict__ Xc,
    const float* __restrict__ Aw,
    const float* __restrict__ ew1, const float* __restrict__ eb1,
    const float* __restrict__ ew2, const float* __restrict__ eb2,
    const float* __restrict__ nw,  const float* __restrict__ nb,
    const float* __restrict__ cw,  const float* __restrict__ cb,
    float* __restrict__ Zout)
{
  __shared__ float sA[16][16], sE1[16][32], sE2[16][16], sNW[16][32];
  __shared__ float sEB1[16], sEB2[16], sNB[16];
  __shared__ float sCW[768][16];
  __shared__ float sCB[768];
  const int tid = threadIdx.x;
  for (int i = tid; i < 256; i += 256) sA[i>>4][i&15] = Aw[i];
  for (int i = tid; i < 512; i += 256) sE1[i>>5][i&31] = ew1[i];
  for (int i = tid; i < 256; i += 256) sE2[i>>4][i&15] = ew2[i];
  for (int i = tid; i < 512; i += 256) sNW[i>>5][i&31] = nw[i];
  if (tid < 16) { sEB1[tid]=eb1[tid]; sEB2[tid]=eb2[tid]; sNB[tid]=nb[tid]; }
  for (int i = tid; i < 768*16; i += 256) sCW[i>>4][i&15] = cw[i];
  for (int i = tid; i < 768; i += 256) sCB[i] = cb[i];
  __syncthreads();
  const int idx = blockIdx.x*256 + tid;           // flat (b*T + t)
  const float* xmp = Xm + (size_t)idx*16;
  const float* xcp = Xc + (size_t)idx*16;
  float xm[16], xc[16];
  #pragma unroll
  for (int j=0;j<4;j++){
    *(f32x4*)&xm[j*4] = *(const f32x4*)(xmp + j*4);
    *(f32x4*)&xc[j*4] = *(const f32x4*)(xcp + j*4);
  }
  float snd[16], rcv[16];
  #pragma unroll
  for (int i=0;i<16;i++){
    float s=0.f, r=0.f;
    #pragma unroll
    for (int j=0;j<16;j++){ s += xm[j]*sA[i][j]; r += xm[j]*sA[j][i]; }
    snd[i]=s; rcv[i]=r;
  }
  float he[16];
  #pragma unroll
  for (int i=0;i<16;i++){
    float a = sEB1[i];
    #pragma unroll
    for (int k=0;k<16;k++) a += snd[k]*sE1[i][k];
    #pragma unroll
    for (int k=0;k<16;k++) a += rcv[k]*sE1[i][16+k];
    he[i] = fmaxf(a, 0.f);
  }
  float he2[16];
  #pragma unroll
  for (int i=0;i<16;i++){
    float a = sEB2[i];
    #pragma unroll
    for (int k=0;k<16;k++) a += he[k]*sE2[i][k];
    he2[i] = fmaxf(a, 0.f);
  }
  float* zp = Zout + (size_t)idx*16;
  #pragma unroll
  for (int m=0;m<16;m++){
    float a = sNB[m];
    #pragma unroll
    for (int k=0;k<16;k++) a += xm[k]*sNW[m][k];
    #pragma unroll
    for (int k=0;k<16;k++) a += he2[k]*sNW[m][16+k];
    zp[m] = fmaxf(a, 0.f);
  }
  float cs = 0.f;
  for (int i=0;i<768;i++){
    float a = sCB[i];
    #pragma unroll
    for (int k=0;k<16;k++) a += xc[k]*sCW[i][k];
    cs += fmaxf(a, 0.f);
  }
  g_ctrl[idx] = cs * 0.3f;
}

// ---------------- kernel B: adstock scan + hill + gru-input ----------------
__global__ __launch_bounds__(64) void k_adstock(
    const float* __restrict__ Xm, const float* __restrict__ alpha,
    const float* __restrict__ hill_a, const float* __restrict__ hill_g,
    float* __restrict__ Zio, float* __restrict__ hill_out)
{
  const int gid = blockIdx.x*64 + threadIdx.x;   // (b, m)
  const int b = gid >> 4, m = gid & 15;
  float a  = fminf(fmaxf(alpha[m],  0.f),  1.f);
  float ha = fminf(fmaxf(hill_a[m], 0.1f), 3.f);
  float hg = fminf(fmaxf(hill_g[m], 0.1f), 2.f);
  float gpow = __powf(hg, ha);
  const float* xp = Xm + (size_t)b*T_N*16 + m;
  float prev = 0.f, cmax = 0.f;
  for (int t=0;t<T_N;t++){ float x = xp[(size_t)t*16]; prev = x + a*prev; cmax = fmaxf(cmax, prev); }
  cmax = fmaxf(cmax, 1e-6f);
  float inv = 1.f/cmax;
  prev = 0.f;
  float* zp  = Zio      + (size_t)b*T_N*16 + m;
  float* hp  = hill_out + (size_t)b*T_N*16 + m;
  for (int t=0;t<T_N;t++){
    float x = xp[(size_t)t*16];
    prev = x + a*prev;
    float xn  = fmaxf(prev*inv, 0.f);
    float num = __powf(xn, ha);
    float h   = num / (num + gpow + 1e-8f);
    float z   = zp[(size_t)t*16];
    hp[(size_t)t*16] = h;
    zp[(size_t)t*16] = h + z;
  }
}

// ---------------- kernel C: persistent GRU + fused heads ----------------
// Round-12 body (partial B-register cache) launched as a PLAIN kernel:
// grid 256 = #CUs and 160KB LDS/block force 1 block/CU co-residency without
// the cooperative API (which appears to reject high-VGPR kernels). Roster +
// per-block flags + poll timeouts keep any anomaly fail-visible, not a hang.
__device__ __forceinline__ void poll_flags(unsigned midx, unsigned val) {
  int tries = 0;
  for (;;) {
    unsigned v = __hip_atomic_load(&g_flag[midx], __ATOMIC_RELAXED, __HIP_MEMORY_SCOPE_AGENT);
    if (__ballot(v >= val) == ~0ull) break;
    if (++tries > (1<<18)) break;               // fail-visible, never hang
    if (tries > 8) __builtin_amdgcn_s_sleep(1);
  }
  __builtin_amdgcn_fence(__ATOMIC_ACQUIRE, "workgroup");
}

__global__ __launch_bounds__(256, 1) void k_gru(
    const float* __restrict__ Xc,
    const float* __restrict__ Wih, const float* __restrict__ Whh,
    const float* __restrict__ bih, const float* __restrict__ bhh,
    const float* __restrict__ wraww, const float* __restrict__ wrawb,
    const float* __restrict__ regemb, const float* __restrict__ bias,
    const float* __restrict__ h0,
    float* __restrict__ hillZ,       // = outw region (read until step t, then w_pos)
    float* __restrict__ hill,        // = outc region (read hill, overwrite contrib)
    float* __restrict__ outy)
{
  __shared__ __align__(16) bf16 sW[88*WROW];      // 136,576 B (72 Whh rows + 16 wraww)
  __shared__ __align__(16) bf16 sWih[72*WIHROW];  //   5,760 B
  __shared__ float sGH[32][84];                   //  10,752 B
  __shared__ float sGIN[32][36];                  //   4,608 B
  __shared__ float sHm[32][24];                   //   3,072 B (f32 master h slice)
  __shared__ float sHD[32][17];                   //   2,176 B (head MFMA D tile)
  __shared__ float sBih[72], sBhh[72];            //     576 B
  __shared__ float sWrb[16];                      //      64 B
  __shared__ float sScal[2];                      //       8 B
  __shared__ unsigned sGP[2];                     //       8 B  -> 163,600 total (1 blk/CU)

  const int tid = threadIdx.x;
  const int wave = tid >> 6, lane = tid & 63;
  const int quad = lane >> 4, l16 = lane & 15;

  // runtime group discovery: g = physical XCD (assembler-encoded getreg)
  if (tid == 0) {
    unsigned x;
    asm volatile("s_getreg_b32 %0, hwreg(HW_REG_XCC_ID, 0, 32)" : "=s"(x));
    x &= 7u;
    unsigned slot = __hip_atomic_fetch_add(&g_roster[x], 1u,
                        __ATOMIC_RELAXED, __HIP_MEMORY_SCOPE_AGENT);
    if (slot < 32u)
      __hip_atomic_store(&g_members[x*32u + slot], (unsigned)blockIdx.x,
                         __ATOMIC_RELAXED, __HIP_MEMORY_SCOPE_AGENT);
    sGP[0] = x; sGP[1] = slot & 31u;
    // one-time grid barrier so all member tables are complete
    __hip_atomic_fetch_add(&g_sync, 1u, __ATOMIC_RELEASE, __HIP_MEMORY_SCOPE_AGENT);
    int tries = 0;
    while (__hip_atomic_load(&g_sync, __ATOMIC_ACQUIRE, __HIP_MEMORY_SCOPE_AGENT) < 256u) {
      if (++tries > (1<<20)) break;
      __builtin_amdgcn_s_sleep(1);
    }
  }
  __syncthreads();
  const int g = (int)sGP[0], p = (int)sGP[1];
  const int j0 = p*24;
  // my poll target: member (lane&31)'s flag slot
  const unsigned midx = __hip_atomic_load(&g_members[g*32 + (lane & 31)],
                            __ATOMIC_RELAXED, __HIP_MEMORY_SCOPE_AGENT) * 32u;
  const unsigned myflag = (unsigned)blockIdx.x * 32u;

  // stage B-tile: rows 0..71 = Whh slice (f32->bf16), rows 72..87 = wraww
  for (int c = tid; c < 88*192; c += 256) {
    int rl = c / 192, off = (c - rl*192)*4;
    const float* src = (rl < 72)
        ? &Whh[(size_t)((rl/24)*768 + j0 + (rl%24))*768 + off]
        : &wraww[(size_t)(rl-72)*768 + off];
    f32x4 w = *(const f32x4*)src;
    bf16x4 v; v[0]=(bf16)w[0]; v[1]=(bf16)w[1]; v[2]=(bf16)w[2]; v[3]=(bf16)w[3];
    *(bf16x4*)&sW[rl*WROW + off] = v;
  }
  for (int c = tid; c < 72*8; c += 256) {
    int rl = c >> 3, off = (c & 7)*4;
    int grow = (rl/24)*768 + j0 + (rl%24);
    f32x4 w = *(const f32x4*)&Wih[(size_t)grow*32 + off];
    bf16x4 v; v[0]=(bf16)w[0]; v[1]=(bf16)w[1]; v[2]=(bf16)w[2]; v[3]=(bf16)w[3];
    *(bf16x4*)&sWih[rl*WIHROW + off] = v;
  }
  if (tid < 72) {
    int grow = (tid/24)*768 + j0 + (tid%24);
    sBih[tid] = bih[grow];
    sBhh[tid] = bhh[grow];
  }
  if (tid >= 128 && tid < 144) sWrb[tid-128] = wrawb[tid-128];
  if (wave == 0) {
    float s = 0.f;
    for (int k = lane; k < 768; k += 64) s += regemb[k];  // reg_emb[0]
    #pragma unroll
    for (int off = 32; off; off >>= 1) s += __shfl_xor(s, off, 64);
    if (lane == 0) { sScal[0] = 0.3f*s; sScal[1] = bias[0]; }
  }
  // init h (parity 0): f32 master + bf16 publish (plain stores -> XCD L2)
  {
    unsigned* hb = (unsigned*)g_hbuf;
    for (int e = tid; e < 384; e += 256) {
      int b = e/12, j = (e - b*12)*2;
      float f0 = h0[j0+j], f1 = h0[j0+j+1];
      sHm[b][j] = f0; sHm[b][j+1] = f1;
      union { bf16 h[2]; unsigned u; } pk;
      pk.h[0] = (bf16)f0; pk.h[1] = (bf16)f1;
      hb[((size_t)(g*32+b)*H_N + j0 + j) >> 1] = pk.u;
    }
  }
  __syncthreads();   // drains init publishes (vmcnt(0)) + LDS staging
  if (tid == 0)
    __hip_atomic_store(&g_flag[myflag], 1u, __ATOMIC_RELAXED, __HIP_MEMORY_SCOPE_AGENT);

  const int mi = wave >> 1;
  const bool lowN = !(wave & 1);
  const int batch_l = l16 + mi*16;
  const int gb = g*32 + batch_l;
  const int bq = g*32 + p;
  const float regt = sScal[0], bias0 = sScal[1];
  const int r0 = lowN ? l16        : 48 + l16;
  const int r1 = lowN ? 16 + l16   : min(64 + l16, 71);
  const int rX = lowN ? 32 + l16   : 72 + l16;   // 3rd row-set (stays in LDS)
  const int rh = 72 + l16;                       // head rows (tail pass)

  // ---- one-time partial register cache (t-invariant): sets 0,1 + Wih ----
  bf16x8 bw0[24], bw1[24];
  #pragma unroll
  for (int kt = 0; kt < 24; kt++) {
    const int ko = kt*32 + quad*8;
    bw0[kt] = *(const bf16x8*)&sW[r0*WROW + ko];
    bw1[kt] = *(const bf16x8*)&sW[r1*WROW + ko];
  }
  const bf16x8 wf0 = *(const bf16x8*)&sWih[r0*WIHROW + quad*8];
  const bf16x8 wf1 = *(const bf16x8*)&sWih[r1*WIHROW + quad*8];
  const bf16x8 wf2 = lowN ? *(const bf16x8*)&sWih[(32+l16)*WIHROW + quad*8] : wf0;

  float wp0_r = 0.f, hl0_r = 0.f, ct0_r = 0.f;  // t=0 state (lanes tid<16)

  // prologue: prefetch x(0) and hill/ctrl(0)
  f32x4 xf0, xf1;
  {
    const float* hz = hillZ + (size_t)gb*T_N*16;
    const float* xr = Xc    + (size_t)gb*T_N*16;
    const float* src = (quad < 2) ? (hz + quad*8) : (xr + (quad-2)*8);
    xf0 = *(const f32x4*)src;
    xf1 = *(const f32x4*)(src + 4);
  }
  float hl_pf = 0.f, ct_pf = 0.f;
  if (tid < 16) {
    hl_pf = hill[(size_t)bq*T_N*16 + tid];
    if (tid == 0) ct_pf = g_ctrl[(size_t)bq*T_N];
  }

  const bf16* hb_base = g_hbuf;
  int par = 0;
  for (int t = 0; t < T_N; t++) {
    f32x4 a0 = {0.f,0.f,0.f,0.f}, a1 = a0, a2 = a0, gi0 = a0, gi1 = a0, hd = a0;
    // gi = x @ W_ih^T from cached regs (overlaps the wait window)
    {
      bf16x8 ax;
      ax[0]=(bf16)xf0[0]; ax[1]=(bf16)xf0[1]; ax[2]=(bf16)xf0[2]; ax[3]=(bf16)xf0[3];
      ax[4]=(bf16)xf1[0]; ax[5]=(bf16)xf1[1]; ax[6]=(bf16)xf1[2]; ax[7]=(bf16)xf1[3];
      if (lowN) {
        a0 = MFMA16(ax, wf0, a0);
        a1 = MFMA16(ax, wf1, a1);
        a2 = MFMA16(ax, wf2, a2);
      } else {
        gi0 = MFMA16(ax, wf0, gi0);
        gi1 = MFMA16(ax, wf1, gi1);
      }
    }
    // wait: all group members published h_{t-1}
    poll_flags(midx, (unsigned)(t + 1));
    // h volley: 24 x 16B sc0 loads (L1-bypass, XCD-L2 hit), waitcnt-pinned
    bf16x8 hf[24];
    {
      const bf16* hrow = hb_base + (size_t)par*B_N*H_N + (size_t)gb*H_N + quad*8;
      #pragma unroll
      for (int kt = 0; kt < 24; kt++) {
        asm volatile("global_load_dwordx4 %0, %1, off sc0"
                     : "=v"(hf[kt]) : "v"(hrow + kt*32) : "memory");
      }
      asm volatile("s_waitcnt vmcnt(0)"
          : "+v"(hf[0]),"+v"(hf[1]),"+v"(hf[2]),"+v"(hf[3]),
            "+v"(hf[4]),"+v"(hf[5]),"+v"(hf[6]),"+v"(hf[7]) :: "memory");
      asm volatile(""
          : "+v"(hf[8]),"+v"(hf[9]),"+v"(hf[10]),"+v"(hf[11]),
            "+v"(hf[12]),"+v"(hf[13]),"+v"(hf[14]),"+v"(hf[15]));
      asm volatile(""
          : "+v"(hf[16]),"+v"(hf[17]),"+v"(hf[18]),"+v"(hf[19]),
            "+v"(hf[20]),"+v"(hf[21]),"+v"(hf[22]),"+v"(hf[23]));
    }
    // next-step prefetches (latency hidden under MFMA burst)
    {
      const int tn = (t + 1 < T_N) ? t + 1 : T_N - 1;
      const float* hz = hillZ + ((size_t)gb*T_N + tn)*16;
      const float* xr = Xc    + ((size_t)gb*T_N + tn)*16;
      const float* src = (quad < 2) ? (hz + quad*8) : (xr + (quad-2)*8);
      xf0 = *(const f32x4*)src;
      xf1 = *(const f32x4*)(src + 4);
    }
    // gh += h @ W_hh^T over K=768 — sets 0/1 from regs, set 2 from LDS
    #pragma unroll
    for (int kt = 0; kt < 24; kt++) {
      const int ko = kt*32 + quad*8;
      a0 = MFMA16(hf[kt], bw0[kt], a0);
      a1 = MFMA16(hf[kt], bw1[kt], a1);
      if (lowN) a2 = MFMA16(hf[kt], *(const bf16x8*)&sW[rX*WROW + ko], a2);
      else      hd = MFMA16(hf[kt], *(const bf16x8*)&sW[rX*WROW + ko], hd);
    }
    // stage D fragments
    {
      const int rb = mi*16 + quad*4;
      const int c0 = lowN ? l16 : 48 + l16;
      const int c1 = lowN ? 16 + l16 : 64 + l16;
      #pragma unroll
      for (int r = 0; r < 4; r++) {
        sGH[rb + r][c0] = a0[r];
        sGH[rb + r][c1] = a1[r];
        if (lowN) sGH[rb + r][32 + l16] = a2[r];
        else { sGIN[rb + r][l16] = gi0[r]; sGIN[rb + r][16 + l16] = gi1[r];
               sHD[rb + r][l16] = hd[r]; }
      }
    }
    __syncthreads();   // S1
    // epilogue (lanes 0..15) concurrent with gates (threads 32..255)
    if (t > 0 && tid < 16) {
      const int tt = t - 1;
      float wp = softplusf_(sHD[p][tid] + sWrb[tid]);
      float hl = hl_pf;
      if (tt == 0) { wp0_r = wp; hl0_r = hl; ct0_r = ct_pf; }
      else {
        size_t o = (size_t)bq*T_N + tt;
        float cv = hl*wp;
        hillZ[o*16 + tid] = wp;
        hill[o*16 + tid]  = cv;
        float cs = cv;
        cs += __shfl_xor(cs, 8, 64);
        cs += __shfl_xor(cs, 4, 64);
        cs += __shfl_xor(cs, 2, 64);
        cs += __shfl_xor(cs, 1, 64);
        if (tid == 0) outy[o] = cs + ct_pf + regt + bias0;
        if (tt == 1) {
          float w0 = 0.5f*(wp + wp0_r);
          float c0v = hl0_r*w0;
          size_t o0 = (size_t)bq*T_N;
          hillZ[o0*16 + tid] = w0;
          hill[o0*16 + tid]  = c0v;
          float cs0 = c0v;
          cs0 += __shfl_xor(cs0, 8, 64);
          cs0 += __shfl_xor(cs0, 4, 64);
          cs0 += __shfl_xor(cs0, 2, 64);
          cs0 += __shfl_xor(cs0, 1, 64);
          if (tid == 0) outy[o0] = cs0 + ct0_r + regt + bias0;
        }
      }
    }
    // prefetch hill/ctrl for next epilogue (column t; own batch -> no hazard)
    if (tid < 16) {
      hl_pf = hill[((size_t)bq*T_N + t)*16 + tid];
      if (tid == 0) ct_pf = g_ctrl[(size_t)bq*T_N + t];
    }
    // gates -> h_new (pairs); f32 master feedback; plain-store publish (L2)
    if (tid >= 32) {
      unsigned* hnxt = (unsigned*)(g_hbuf + (size_t)(1-par)*B_N*H_N);
      for (int e = tid - 32; e < 384; e += 224) {
        int b = e/12, j = (e - b*12)*2;
        float hn0, hn1;
        {
          float rr = sigmoidf_(sGH[b][j]    + sBih[j]    + sBhh[j]);
          float zz = sigmoidf_(sGH[b][24+j] + sBih[24+j] + sBhh[24+j]);
          float hh = sGH[b][48+j] + sBhh[48+j];
          float in_ = sGIN[b][j]  + sBih[48+j];
          float nn = tanhf_(in_ + rr*hh);
          hn0 = (1.f-zz)*nn + zz*sHm[b][j];
        }
        {
          int j1 = j+1;
          float rr = sigmoidf_(sGH[b][j1]    + sBih[j1]    + sBhh[j1]);
          float zz = sigmoidf_(sGH[b][24+j1] + sBih[24+j1] + sBhh[24+j1]);
          float hh = sGH[b][48+j1] + sBhh[48+j1];
          float in_ = sGIN[b][j1]  + sBih[48+j1];
          float nn = tanhf_(in_ + rr*hh);
          hn1 = (1.f-zz)*nn + zz*sHm[b][j1];
        }
        sHm[b][j] = hn0; sHm[b][j+1] = hn1;
        union { bf16 h[2]; unsigned u; } pk;
        pk.h[0] = (bf16)hn0; pk.h[1] = (bf16)hn1;
        hnxt[((size_t)(g*32+b)*H_N + j0 + j) >> 1] = pk.u;
      }
    }
    __syncthreads();   // S2: vmcnt(0) drains publishes into L2
    if (tid == 0)
      __hip_atomic_store(&g_flag[myflag], (unsigned)(t + 2), __ATOMIC_RELAXED, __HIP_MEMORY_SCOPE_AGENT);
    par ^= 1;
  }
  // tail: head for tt = T-1 from h_seq[T-1] (LDS head rows — cold path)
  if (wave & 1) {
    poll_flags(midx, (unsigned)(T_N + 1));
    const bf16* hrow = hb_base + (size_t)par*B_N*H_N + (size_t)gb*H_N + quad*8;
    f32x4 hd = {0.f,0.f,0.f,0.f};
    bf16x8 hf[24];
    #pragma unroll
    for (int kt = 0; kt < 24; kt++) {
      asm volatile("global_load_dwordx4 %0, %1, off sc0"
                   : "=v"(hf[kt]) : "v"(hrow + kt*32) : "memory");
    }
    asm volatile("s_waitcnt vmcnt(0)"
        : "+v"(hf[0]),"+v"(hf[1]),"+v"(hf[2]),"+v"(hf[3]),
          "+v"(hf[4]),"+v"(hf[5]),"+v"(hf[6]),"+v"(hf[7]) :: "memory");
    asm volatile(""
        : "+v"(hf[8]),"+v"(hf[9]),"+v"(hf[10]),"+v"(hf[11]),
          "+v"(hf[12]),"+v"(hf[13]),"+v"(hf[14]),"+v"(hf[15]));
    asm volatile(""
        : "+v"(hf[16]),"+v"(hf[17]),"+v"(hf[18]),"+v"(hf[19]),
          "+v"(hf[20]),"+v"(hf[21]),"+v"(hf[22]),"+v"(hf[23]));
    #pragma unroll
    for (int kt = 0; kt < 24; kt++) {
      const int ko = kt*32 + quad*8;
      hd = MFMA16(hf[kt], *(const bf16x8*)&sW[rh*WROW + ko], hd);
    }
    const int rb = mi*16 + quad*4;
    #pragma unroll
    for (int r = 0; r < 4; r++) sHD[rb + r][l16] = hd[r];
  }
  __syncthreads();
  if (tid < 16) {
    const int tt = T_N - 1;
    float wp = softplusf_(sHD[p][tid] + sWrb[tid]);
    float hl = hill[((size_t)bq*T_N + tt)*16 + tid];
    size_t o = (size_t)bq*T_N + tt;
    float cv = hl*wp;
    hillZ[o*16 + tid] = wp;
    hill[o*16 + tid]  = cv;
    float cs = cv;
    cs += __shfl_xor(cs, 8, 64);
    cs += __shfl_xor(cs, 4, 64);
    cs += __shfl_xor(cs, 2, 64);
    cs += __shfl_xor(cs, 1, 64);
    if (tid == 0) outy[o] = cs + g_ctrl[o] + regt + bias0;
  }
}

extern "C" void kernel_launch(void* const* d_in, const int* in_sizes, int n_in,
                              void* d_out, int out_size, void* d_ws, size_t ws_size,
                              hipStream_t stream) {
  const float* Xm    = (const float*)d_in[0];
  const float* Xc    = (const float*)d_in[1];
  const float* Aw    = (const float*)d_in[3];
  const float* ew1   = (const float*)d_in[4];
  const float* eb1   = (const float*)d_in[5];
  const float* ew2   = (const float*)d_in[6];
  const float* eb2   = (const float*)d_in[7];
  const float* nw    = (const float*)d_in[8];
  const float* nb    = (const float*)d_in[9];
  const float* Wih   = (const float*)d_in[10];
  const float* Whh   = (const float*)d_in[11];
  const float* bih   = (const float*)d_in[12];
  const float* bhh   = (const float*)d_in[13];
  const float* wraww = (const float*)d_in[14];
  const float* wrawb = (const float*)d_in[15];
  const float* alpha = (const float*)d_in[16];
  const float* hilla = (const float*)d_in[17];
  const float* hillg = (const float*)d_in[18];
  const float* cw    = (const float*)d_in[19];
  const float* cb    = (const float*)d_in[20];
  const float* regemb= (const float*)d_in[21];
  const float* bias  = (const float*)d_in[22];
  const float* h0    = (const float*)d_in[23];

  float* outy = (float*)d_out;
  float* outw = outy + 256*512;          // doubles as Z / hillZ scratch
  float* outc = outw + 256*512*16;       // doubles as hill scratch

  k_zero<<<1, 256, 0, stream>>>();
  k_encode<<<512, 256, 0, stream>>>(Xm, Xc, Aw, ew1, eb1, ew2, eb2, nw, nb, cw, cb,
                                    outw);
  k_adstock<<<64, 64, 0, stream>>>(Xm, alpha, hilla, hillg, outw, outc);
  // Plain launch: grid==256 CUs + 160KB-LDS clamp => all blocks co-resident.
  // (hipLaunchCooperativeKernel rejects this kernel at high VGPR counts.)
  k_gru<<<dim3(256), dim3(256), 0, stream>>>(
      Xc, Wih, Whh, bih, bhh, wraww, wrawb, regemb, bias, h0,
      outw, outc, outy);
}

// Round 15
// 3574.524 us; speedup vs baseline: 2.0688x; 1.1305x over previous
//
#include <hip/hip_runtime.h>

typedef __bf16 bf16;
typedef bf16 bf16x8 __attribute__((ext_vector_type(8)));
typedef bf16 bf16x4 __attribute__((ext_vector_type(4)));
typedef float f32x4 __attribute__((ext_vector_type(4)));

#define MFMA16(a,b,c) __builtin_amdgcn_mfma_f32_16x16x32_bf16((a),(b),(c),0,0,0)

#define B_N 256
#define T_N 512
#define H_N 768
#define WROW 776      // 768 + 8 pad
#define WIHROW 40     // 32 + 8 pad

// ---- device-global scratch (BSS) ----
__device__ float    g_ctrl[B_N * T_N];          // 512 KB
__device__ bf16     g_hbuf[2 * B_N * H_N];      // 768 KB (bf16 h exchange, intra-XCD L2)
__device__ unsigned g_flag[256 * 32];           // per-BLOCK flag, 128B apart (MALL atomics)
__device__ unsigned g_members[8 * 32];          // XCD roster -> blockIdx table
__device__ unsigned g_roster[8];
__device__ unsigned g_sync;

__device__ __forceinline__ float sigmoidf_(float x){ return 1.f/(1.f+__expf(-x)); }
__device__ __forceinline__ float tanhf_(float x){
  float e = __expf(-2.f*fabsf(x));
  float t = (1.f-e)/(1.f+e);
  return copysignf(t, x);
}
__device__ __forceinline__ float softplusf_(float x){
  return x > 20.f ? x : log1pf(__expf(x));
}

__global__ void k_zero() {
  const int tid = threadIdx.x;
  for (int i = tid; i < 256*32; i += 256) g_flag[i] = 0u;
  if (tid < 256) g_members[tid & 255] = 0u;   // fallback: block 0's flag (always advances)
  if (tid < 8)   g_roster[tid] = 0u;
  if (tid == 0)  g_sync = 0u;
}

// ---------------- kernel A: causal encoder Z + ctrl term ----------------
__global__ __launch_bounds__(256) void k_encode(
    const float* __restrict__ Xm, const float* __restrict__ Xc,
    const float* __restrict__ Aw,
    const float* __restrict__ ew1, const float* __restrict__ eb1,
    const float* __restrict__ ew2, const float* __restrict__ eb2,
    const float* __restrict__ nw,  const float* __restrict__ nb,
    const float* __restrict__ cw,  const float* __restrict__ cb,
    float* __restrict__ Zout)
{
  __shared__ float sA[16][16], sE1[16][32], sE2[16][16], sNW[16][32];
  __shared__ float sEB1[16], sEB2[16], sNB[16];
  __shared__ float sCW[768][16];
  __shared__ float sCB[768];
  const int tid = threadIdx.x;
  for (int i = tid; i < 256; i += 256) sA[i>>4][i&15] = Aw[i];
  for (int i = tid; i < 512; i += 256) sE1[i>>5][i&31] = ew1[i];
  for (int i = tid; i < 256; i += 256) sE2[i>>4][i&15] = ew2[i];
  for (int i = tid; i < 512; i += 256) sNW[i>>5][i&31] = nw[i];
  if (tid < 16) { sEB1[tid]=eb1[tid]; sEB2[tid]=eb2[tid]; sNB[tid]=nb[tid]; }
  for (int i = tid; i < 768*16; i += 256) sCW[i>>4][i&15] = cw[i];
  for (int i = tid; i < 768; i += 256) sCB[i] = cb[i];
  __syncthreads();
  const int idx = blockIdx.x*256 + tid;           // flat (b*T + t)
  const float* xmp = Xm + (size_t)idx*16;
  const float* xcp = Xc + (size_t)idx*16;
  float xm[16], xc[16];
  #pragma unroll
  for (int j=0;j<4;j++){
    *(f32x4*)&xm[j*4] = *(const f32x4*)(xmp + j*4);
    *(f32x4*)&xc[j*4] = *(const f32x4*)(xcp + j*4);
  }
  float snd[16], rcv[16];
  #pragma unroll
  for (int i=0;i<16;i++){
    float s=0.f, r=0.f;
    #pragma unroll
    for (int j=0;j<16;j++){ s += xm[j]*sA[i][j]; r += xm[j]*sA[j][i]; }
    snd[i]=s; rcv[i]=r;
  }
  float he[16];
  #pragma unroll
  for (int i=0;i<16;i++){
    float a = sEB1[i];
    #pragma unroll
    for (int k=0;k<16;k++) a += snd[k]*sE1[i][k];
    #pragma unroll
    for (int k=0;k<16;k++) a += rcv[k]*sE1[i][16+k];
    he[i] = fmaxf(a, 0.f);
  }
  float he2[16];
  #pragma unroll
  for (int i=0;i<16;i++){
    float a = sEB2[i];
    #pragma unroll
    for (int k=0;k<16;k++) a += he[k]*sE2[i][k];
    he2[i] = fmaxf(a, 0.f);
  }
  float* zp = Zout + (size_t)idx*16;
  #pragma unroll
  for (int m=0;m<16;m++){
    float a = sNB[m];
    #pragma unroll
    for (int k=0;k<16;k++) a += xm[k]*sNW[m][k];
    #pragma unroll
    for (int k=0;k<16;k++) a += he2[k]*sNW[m][16+k];
    zp[m] = fmaxf(a, 0.f);
  }
  float cs = 0.f;
  for (int i=0;i<768;i++){
    float a = sCB[i];
    #pragma unroll
    for (int k=0;k<16;k++) a += xc[k]*sCW[i][k];
    cs += fmaxf(a, 0.f);
  }
  g_ctrl[idx] = cs * 0.3f;
}

// ---------------- kernel B: adstock scan + hill + gru-input ----------------
__global__ __launch_bounds__(64) void k_adstock(
    const float* __restrict__ Xm, const float* __restrict__ alpha,
    const float* __restrict__ hill_a, const float* __restrict__ hill_g,
    float* __restrict__ Zio, float* __restrict__ hill_out)
{
  const int gid = blockIdx.x*64 + threadIdx.x;   // (b, m)
  const int b = gid >> 4, m = gid & 15;
  float a  = fminf(fmaxf(alpha[m],  0.f),  1.f);
  float ha = fminf(fmaxf(hill_a[m], 0.1f), 3.f);
  float hg = fminf(fmaxf(hill_g[m], 0.1f), 2.f);
  float gpow = __powf(hg, ha);
  const float* xp = Xm + (size_t)b*T_N*16 + m;
  float prev = 0.f, cmax = 0.f;
  for (int t=0;t<T_N;t++){ float x = xp[(size_t)t*16]; prev = x + a*prev; cmax = fmaxf(cmax, prev); }
  cmax = fmaxf(cmax, 1e-6f);
  float inv = 1.f/cmax;
  prev = 0.f;
  float* zp  = Zio      + (size_t)b*T_N*16 + m;
  float* hp  = hill_out + (size_t)b*T_N*16 + m;
  for (int t=0;t<T_N;t++){
    float x = xp[(size_t)t*16];
    prev = x + a*prev;
    float xn  = fmaxf(prev*inv, 0.f);
    float num = __powf(xn, ha);
    float h   = num / (num + gpow + 1e-8f);
    float z   = zp[(size_t)t*16];
    hp[(size_t)t*16] = h;
    zp[(size_t)t*16] = h + z;
  }
}

// ---------------- kernel C: persistent GRU + fused heads ----------------
// Round-13 structure (proven 3.70ms): XCD-roster groups, h via plain-store/
// sc0-load intra-XCD L2, flags via MALL agent atomics (sc0 polling of a hot
// line is UNSAFE — L1 serves stale hits; learned round 14). NEW vs r13: the
// per-step epilogue is deferred past the flag store (sHD grabbed to regs
// pre-S2) so wave 0's softplus/HBM-store drain overlaps other blocks' polls.
__device__ __forceinline__ void poll_flags(unsigned midx, unsigned val) {
  int tries = 0;
  for (;;) {
    unsigned v = __hip_atomic_load(&g_flag[midx], __ATOMIC_RELAXED, __HIP_MEMORY_SCOPE_AGENT);
    if (__ballot(v >= val) == ~0ull) break;
    if (++tries > (1<<18)) break;               // fail-visible, never hang
    if (tries > 8) __builtin_amdgcn_s_sleep(1);
  }
  __builtin_amdgcn_fence(__ATOMIC_ACQUIRE, "workgroup");
}

__global__ __launch_bounds__(256, 1) void k_gru(
    const float* __restrict__ Xc,
    const float* __restrict__ Wih, const float* __restrict__ Whh,
    const float* __restrict__ bih, const float* __restrict__ bhh,
    const float* __restrict__ wraww, const float* __restrict__ wrawb,
    const float* __restrict__ regemb, const float* __restrict__ bias,
    const float* __restrict__ h0,
    float* __restrict__ hillZ,       // = outw region (read until step t, then w_pos)
    float* __restrict__ hill,        // = outc region (read hill, overwrite contrib)
    float* __restrict__ outy)
{
  __shared__ __align__(16) bf16 sW[88*WROW];      // 136,576 B (72 Whh rows + 16 wraww)
  __shared__ __align__(16) bf16 sWih[72*WIHROW];  //   5,760 B
  __shared__ float sGH[32][84];                   //  10,752 B
  __shared__ float sGIN[32][36];                  //   4,608 B
  __shared__ float sHm[32][24];                   //   3,072 B (f32 master h slice)
  __shared__ float sHD[32][17];                   //   2,176 B (head MFMA D tile)
  __shared__ float sBih[72], sBhh[72];            //     576 B
  __shared__ float sWrb[16];                      //      64 B
  __shared__ float sScal[2];                      //       8 B
  __shared__ unsigned sGP[2];                     //       8 B  -> 163,600 total (1 blk/CU)

  const int tid = threadIdx.x;
  const int wave = tid >> 6, lane = tid & 63;
  const int quad = lane >> 4, l16 = lane & 15;

  // runtime group discovery: g = physical XCD (assembler-encoded getreg)
  if (tid == 0) {
    unsigned x;
    asm volatile("s_getreg_b32 %0, hwreg(HW_REG_XCC_ID, 0, 32)" : "=s"(x));
    x &= 7u;
    unsigned slot = __hip_atomic_fetch_add(&g_roster[x], 1u,
                        __ATOMIC_RELAXED, __HIP_MEMORY_SCOPE_AGENT);
    if (slot < 32u)
      __hip_atomic_store(&g_members[x*32u + slot], (unsigned)blockIdx.x,
                         __ATOMIC_RELAXED, __HIP_MEMORY_SCOPE_AGENT);
    sGP[0] = x; sGP[1] = slot & 31u;
    // one-time grid barrier so all member tables are complete
    __hip_atomic_fetch_add(&g_sync, 1u, __ATOMIC_RELEASE, __HIP_MEMORY_SCOPE_AGENT);
    int tries = 0;
    while (__hip_atomic_load(&g_sync, __ATOMIC_ACQUIRE, __HIP_MEMORY_SCOPE_AGENT) < 256u) {
      if (++tries > (1<<20)) break;
      __builtin_amdgcn_s_sleep(1);
    }
  }
  __syncthreads();
  const int g = (int)sGP[0], p = (int)sGP[1];
  const int j0 = p*24;
  // my poll target: member (lane&31)'s flag slot
  const unsigned midx = __hip_atomic_load(&g_members[g*32 + (lane & 31)],
                            __ATOMIC_RELAXED, __HIP_MEMORY_SCOPE_AGENT) * 32u;
  const unsigned myflag = (unsigned)blockIdx.x * 32u;

  // stage B-tile: rows 0..71 = Whh slice (f32->bf16), rows 72..87 = wraww
  for (int c = tid; c < 88*192; c += 256) {
    int rl = c / 192, off = (c - rl*192)*4;
    const float* src = (rl < 72)
        ? &Whh[(size_t)((rl/24)*768 + j0 + (rl%24))*768 + off]
        : &wraww[(size_t)(rl-72)*768 + off];
    f32x4 w = *(const f32x4*)src;
    bf16x4 v; v[0]=(bf16)w[0]; v[1]=(bf16)w[1]; v[2]=(bf16)w[2]; v[3]=(bf16)w[3];
    *(bf16x4*)&sW[rl*WROW + off] = v;
  }
  for (int c = tid; c < 72*8; c += 256) {
    int rl = c >> 3, off = (c & 7)*4;
    int grow = (rl/24)*768 + j0 + (rl%24);
    f32x4 w = *(const f32x4*)&Wih[(size_t)grow*32 + off];
    bf16x4 v; v[0]=(bf16)w[0]; v[1]=(bf16)w[1]; v[2]=(bf16)w[2]; v[3]=(bf16)w[3];
    *(bf16x4*)&sWih[rl*WIHROW + off] = v;
  }
  if (tid < 72) {
    int grow = (tid/24)*768 + j0 + (tid%24);
    sBih[tid] = bih[grow];
    sBhh[tid] = bhh[grow];
  }
  if (tid >= 128 && tid < 144) sWrb[tid-128] = wrawb[tid-128];
  if (wave == 0) {
    float s = 0.f;
    for (int k = lane; k < 768; k += 64) s += regemb[k];  // reg_emb[0]
    #pragma unroll
    for (int off = 32; off; off >>= 1) s += __shfl_xor(s, off, 64);
    if (lane == 0) { sScal[0] = 0.3f*s; sScal[1] = bias[0]; }
  }
  // init h (parity 0): f32 master + bf16 publish (plain stores -> XCD L2)
  {
    unsigned* hb = (unsigned*)g_hbuf;
    for (int e = tid; e < 384; e += 256) {
      int b = e/12, j = (e - b*12)*2;
      float f0 = h0[j0+j], f1 = h0[j0+j+1];
      sHm[b][j] = f0; sHm[b][j+1] = f1;
      union { bf16 h[2]; unsigned u; } pk;
      pk.h[0] = (bf16)f0; pk.h[1] = (bf16)f1;
      hb[((size_t)(g*32+b)*H_N + j0 + j) >> 1] = pk.u;
    }
  }
  __syncthreads();   // drains init publishes (vmcnt(0)) + LDS staging
  if (tid == 0)
    __hip_atomic_store(&g_flag[myflag], 1u, __ATOMIC_RELAXED, __HIP_MEMORY_SCOPE_AGENT);

  const int mi = wave >> 1;
  const bool lowN = !(wave & 1);
  const int batch_l = l16 + mi*16;
  const int gb = g*32 + batch_l;
  const int bq = g*32 + p;
  const float regt = sScal[0], bias0 = sScal[1];
  const int r0 = lowN ? l16        : 48 + l16;
  const int r1 = lowN ? 16 + l16   : min(64 + l16, 71);
  const int rX = lowN ? 32 + l16   : 72 + l16;   // 3rd row-set (stays in LDS)
  const int rh = 72 + l16;                       // head rows (tail pass)

  // ---- one-time partial register cache (t-invariant): sets 0,1 + Wih ----
  bf16x8 bw0[24], bw1[24];
  #pragma unroll
  for (int kt = 0; kt < 24; kt++) {
    const int ko = kt*32 + quad*8;
    bw0[kt] = *(const bf16x8*)&sW[r0*WROW + ko];
    bw1[kt] = *(const bf16x8*)&sW[r1*WROW + ko];
  }
  const bf16x8 wf0 = *(const bf16x8*)&sWih[r0*WIHROW + quad*8];
  const bf16x8 wf1 = *(const bf16x8*)&sWih[r1*WIHROW + quad*8];
  const bf16x8 wf2 = lowN ? *(const bf16x8*)&sWih[(32+l16)*WIHROW + quad*8] : wf0;

  float wp0_r = 0.f, hl0_r = 0.f, ct0_r = 0.f;  // t=0 state (lanes tid<16)

  // prologue: prefetch x(0) and hill/ctrl(0)
  f32x4 xf0, xf1;
  {
    const float* hz = hillZ + (size_t)gb*T_N*16;
    const float* xr = Xc    + (size_t)gb*T_N*16;
    const float* src = (quad < 2) ? (hz + quad*8) : (xr + (quad-2)*8);
    xf0 = *(const f32x4*)src;
    xf1 = *(const f32x4*)(src + 4);
  }
  float hl_pf = 0.f, ct_pf = 0.f;
  if (tid < 16) {
    hl_pf = hill[(size_t)bq*T_N*16 + tid];
    if (tid == 0) ct_pf = g_ctrl[(size_t)bq*T_N];
  }

  const bf16* hb_base = g_hbuf;
  int par = 0;
  for (int t = 0; t < T_N; t++) {
    f32x4 a0 = {0.f,0.f,0.f,0.f}, a1 = a0, a2 = a0, gi0 = a0, gi1 = a0, hd = a0;
    // gi = x @ W_ih^T from cached regs (overlaps the wait window)
    {
      bf16x8 ax;
      ax[0]=(bf16)xf0[0]; ax[1]=(bf16)xf0[1]; ax[2]=(bf16)xf0[2]; ax[3]=(bf16)xf0[3];
      ax[4]=(bf16)xf1[0]; ax[5]=(bf16)xf1[1]; ax[6]=(bf16)xf1[2]; ax[7]=(bf16)xf1[3];
      if (lowN) {
        a0 = MFMA16(ax, wf0, a0);
        a1 = MFMA16(ax, wf1, a1);
        a2 = MFMA16(ax, wf2, a2);
      } else {
        gi0 = MFMA16(ax, wf0, gi0);
        gi1 = MFMA16(ax, wf1, gi1);
      }
    }
    // wait: all group members published h_{t-1} (MALL flags — proven path)
    poll_flags(midx, (unsigned)(t + 1));
    // h volley: 24 x 16B sc0 loads (L1-bypass OK here: lines never L1-hot),
    // waitcnt-pinned
    bf16x8 hf[24];
    {
      const bf16* hrow = hb_base + (size_t)par*B_N*H_N + (size_t)gb*H_N + quad*8;
      #pragma unroll
      for (int kt = 0; kt < 24; kt++) {
        asm volatile("global_load_dwordx4 %0, %1, off sc0"
                     : "=v"(hf[kt]) : "v"(hrow + kt*32) : "memory");
      }
      asm volatile("s_waitcnt vmcnt(0)"
          : "+v"(hf[0]),"+v"(hf[1]),"+v"(hf[2]),"+v"(hf[3]),
            "+v"(hf[4]),"+v"(hf[5]),"+v"(hf[6]),"+v"(hf[7]) :: "memory");
      asm volatile(""
          : "+v"(hf[8]),"+v"(hf[9]),"+v"(hf[10]),"+v"(hf[11]),
            "+v"(hf[12]),"+v"(hf[13]),"+v"(hf[14]),"+v"(hf[15]));
      asm volatile(""
          : "+v"(hf[16]),"+v"(hf[17]),"+v"(hf[18]),"+v"(hf[19]),
            "+v"(hf[20]),"+v"(hf[21]),"+v"(hf[22]),"+v"(hf[23]));
    }
    // next-step prefetches (latency hidden under MFMA burst)
    {
      const int tn = (t + 1 < T_N) ? t + 1 : T_N - 1;
      const float* hz = hillZ + ((size_t)gb*T_N + tn)*16;
      const float* xr = Xc    + ((size_t)gb*T_N + tn)*16;
      const float* src = (quad < 2) ? (hz + quad*8) : (xr + (quad-2)*8);
      xf0 = *(const f32x4*)src;
      xf1 = *(const f32x4*)(src + 4);
    }
    // gh += h @ W_hh^T over K=768 — sets 0/1 from regs, set 2 from LDS
    #pragma unroll
    for (int kt = 0; kt < 24; kt++) {
      const int ko = kt*32 + quad*8;
      a0 = MFMA16(hf[kt], bw0[kt], a0);
      a1 = MFMA16(hf[kt], bw1[kt], a1);
      if (lowN) a2 = MFMA16(hf[kt], *(const bf16x8*)&sW[rX*WROW + ko], a2);
      else      hd = MFMA16(hf[kt], *(const bf16x8*)&sW[rX*WROW + ko], hd);
    }
    // stage D fragments
    {
      const int rb = mi*16 + quad*4;
      const int c0 = lowN ? l16 : 48 + l16;
      const int c1 = lowN ? 16 + l16 : 64 + l16;
      #pragma unroll
      for (int r = 0; r < 4; r++) {
        sGH[rb + r][c0] = a0[r];
        sGH[rb + r][c1] = a1[r];
        if (lowN) sGH[rb + r][32 + l16] = a2[r];
        else { sGIN[rb + r][l16] = gi0[r]; sGIN[rb + r][16 + l16] = gi1[r];
               sHD[rb + r][l16] = hd[r]; }
      }
    }
    __syncthreads();   // S1
    // grab head value to regs (epilogue itself deferred past the flag store;
    // safe: next sHD write happens after this block's S2)
    float hd_s = 0.f;
    if (tid < 16) hd_s = sHD[p][tid];
    // gates -> h_new (pairs); f32 master feedback; plain-store publish (L2)
    if (tid >= 32) {
      unsigned* hnxt = (unsigned*)(g_hbuf + (size_t)(1-par)*B_N*H_N);
      for (int e = tid - 32; e < 384; e += 224) {
        int b = e/12, j = (e - b*12)*2;
        float hn0, hn1;
        {
          float rr = sigmoidf_(sGH[b][j]    + sBih[j]    + sBhh[j]);
          float zz = sigmoidf_(sGH[b][24+j] + sBih[24+j] + sBhh[24+j]);
          float hh = sGH[b][48+j] + sBhh[48+j];
          float in_ = sGIN[b][j]  + sBih[48+j];
          float nn = tanhf_(in_ + rr*hh);
          hn0 = (1.f-zz)*nn + zz*sHm[b][j];
        }
        {
          int j1 = j+1;
          float rr = sigmoidf_(sGH[b][j1]    + sBih[j1]    + sBhh[j1]);
          float zz = sigmoidf_(sGH[b][24+j1] + sBih[24+j1] + sBhh[24+j1]);
          float hh = sGH[b][48+j1] + sBhh[48+j1];
          float in_ = sGIN[b][j1]  + sBih[48+j1];
          float nn = tanhf_(in_ + rr*hh);
          hn1 = (1.f-zz)*nn + zz*sHm[b][j1];
        }
        sHm[b][j] = hn0; sHm[b][j+1] = hn1;
        union { bf16 h[2]; unsigned u; } pk;
        pk.h[0] = (bf16)hn0; pk.h[1] = (bf16)hn1;
        hnxt[((size_t)(g*32+b)*H_N + j0 + j) >> 1] = pk.u;
      }
    }
    __syncthreads();   // S2: vmcnt(0) drains publishes into L2
    if (tid == 0)
      __hip_atomic_store(&g_flag[myflag], (unsigned)(t + 2), __ATOMIC_RELAXED, __HIP_MEMORY_SCOPE_AGENT);
    // ---- deferred epilogue for tt = t-1: overlaps other blocks' polls ----
    if (t > 0 && tid < 16) {
      const int tt = t - 1;
      float wp = softplusf_(hd_s + sWrb[tid]);
      float hl = hl_pf;
      if (tt == 0) { wp0_r = wp; hl0_r = hl; ct0_r = ct_pf; }
      else {
        size_t o = (size_t)bq*T_N + tt;
        float cv = hl*wp;
        hillZ[o*16 + tid] = wp;
        hill[o*16 + tid]  = cv;
        float cs = cv;
        cs += __shfl_xor(cs, 8, 64);
        cs += __shfl_xor(cs, 4, 64);
        cs += __shfl_xor(cs, 2, 64);
        cs += __shfl_xor(cs, 1, 64);
        if (tid == 0) outy[o] = cs + ct_pf + regt + bias0;
        if (tt == 1) {
          float w0 = 0.5f*(wp + wp0_r);
          float c0v = hl0_r*w0;
          size_t o0 = (size_t)bq*T_N;
          hillZ[o0*16 + tid] = w0;
          hill[o0*16 + tid]  = c0v;
          float cs0 = c0v;
          cs0 += __shfl_xor(cs0, 8, 64);
          cs0 += __shfl_xor(cs0, 4, 64);
          cs0 += __shfl_xor(cs0, 2, 64);
          cs0 += __shfl_xor(cs0, 1, 64);
          if (tid == 0) outy[o0] = cs0 + ct0_r + regt + bias0;
        }
      }
    }
    // prefetch hill/ctrl for next epilogue (column t; own batch -> no hazard)
    if (tid < 16) {
      hl_pf = hill[((size_t)bq*T_N + t)*16 + tid];
      if (tid == 0) ct_pf = g_ctrl[(size_t)bq*T_N + t];
    }
    par ^= 1;
  }
  // tail: head for tt = T-1 from h_seq[T-1] (LDS head rows — cold path)
  if (wave & 1) {
    poll_flags(midx, (unsigned)(T_N + 1));
    const bf16* hrow = hb_base + (size_t)par*B_N*H_N + (size_t)gb*H_N + quad*8;
    f32x4 hd = {0.f,0.f,0.f,0.f};
    bf16x8 hf[24];
    #pragma unroll
    for (int kt = 0; kt < 24; kt++) {
      asm volatile("global_load_dwordx4 %0, %1, off sc0"
                   : "=v"(hf[kt]) : "v"(hrow + kt*32) : "memory");
    }
    asm volatile("s_waitcnt vmcnt(0)"
        : "+v"(hf[0]),"+v"(hf[1]),"+v"(hf[2]),"+v"(hf[3]),
          "+v"(hf[4]),"+v"(hf[5]),"+v"(hf[6]),"+v"(hf[7]) :: "memory");
    asm volatile(""
        : "+v"(hf[8]),"+v"(hf[9]),"+v"(hf[10]),"+v"(hf[11]),
          "+v"(hf[12]),"+v"(hf[13]),"+v"(hf[14]),"+v"(hf[15]));
    asm volatile(""
        : "+v"(hf[16]),"+v"(hf[17]),"+v"(hf[18]),"+v"(hf[19]),
          "+v"(hf[20]),"+v"(hf[21]),"+v"(hf[22]),"+v"(hf[23]));
    #pragma unroll
    for (int kt = 0; kt < 24; kt++) {
      const int ko = kt*32 + quad*8;
      hd = MFMA16(hf[kt], *(const bf16x8*)&sW[rh*WROW + ko], hd);
    }
    const int rb = mi*16 + quad*4;
    #pragma unroll
    for (int r = 0; r < 4; r++) sHD[rb + r][l16] = hd[r];
  }
  __syncthreads();
  if (tid < 16) {
    const int tt = T_N - 1;
    float wp = softplusf_(sHD[p][tid] + sWrb[tid]);
    float hl = hill[((size_t)bq*T_N + tt)*16 + tid];
    size_t o = (size_t)bq*T_N + tt;
    float cv = hl*wp;
    hillZ[o*16 + tid] = wp;
    hill[o*16 + tid]  = cv;
    float cs = cv;
    cs += __shfl_xor(cs, 8, 64);
    cs += __shfl_xor(cs, 4, 64);
    cs += __shfl_xor(cs, 2, 64);
    cs += __shfl_xor(cs, 1, 64);
    if (tid == 0) outy[o] = cs + g_ctrl[o] + regt + bias0;
  }
}

extern "C" void kernel_launch(void* const* d_in, const int* in_sizes, int n_in,
                              void* d_out, int out_size, void* d_ws, size_t ws_size,
                              hipStream_t stream) {
  const float* Xm    = (const float*)d_in[0];
  const float* Xc    = (const float*)d_in[1];
  const float* Aw    = (const float*)d_in[3];
  const float* ew1   = (const float*)d_in[4];
  const float* eb1   = (const float*)d_in[5];
  const float* ew2   = (const float*)d_in[6];
  const float* eb2   = (const float*)d_in[7];
  const float* nw    = (const float*)d_in[8];
  const float* nb    = (const float*)d_in[9];
  const float* Wih   = (const float*)d_in[10];
  const float* Whh   = (const float*)d_in[11];
  const float* bih   = (const float*)d_in[12];
  const float* bhh   = (const float*)d_in[13];
  const float* wraww = (const float*)d_in[14];
  const float* wrawb = (const float*)d_in[15];
  const float* alpha = (const float*)d_in[16];
  const float* hilla = (const float*)d_in[17];
  const float* hillg = (const float*)d_in[18];
  const float* cw    = (const float*)d_in[19];
  const float* cb    = (const float*)d_in[20];
  const float* regemb= (const float*)d_in[21];
  const float* bias  = (const float*)d_in[22];
  const float* h0    = (const float*)d_in[23];

  float* outy = (float*)d_out;
  float* outw = outy + 256*512;          // doubles as Z / hillZ scratch
  float* outc = outw + 256*512*16;       // doubles as hill scratch

  k_zero<<<1, 256, 0, stream>>>();
  k_encode<<<512, 256, 0, stream>>>(Xm, Xc, Aw, ew1, eb1, ew2, eb2, nw, nb, cw, cb,
                                    outw);
  k_adstock<<<64, 64, 0, stream>>>(Xm, alpha, hilla, hillg, outw, outc);
  // Plain launch: grid==256 CUs + 160KB-LDS clamp => all blocks co-resident.
  k_gru<<<dim3(256), dim3(256), 0, stream>>>(
      Xc, Wih, Whh, bih, bhh, wraww, wrawb, regemb, bias, h0,
      outw, outc, outy);
}